// Round 14
// baseline (373.395 us; speedup 1.0000x reference)
//
#include <hip/hip_runtime.h>
#include <cstddef>
#include <cstdint>

#define B_ 4
#define N_ 1024
#define C_ 768
#define H_ 12
#define D_ 64

typedef __attribute__((ext_vector_type(8))) short bf16x8;
typedef __attribute__((ext_vector_type(4))) short s16x4;
typedef __attribute__((ext_vector_type(4))) float f32x4;
typedef __attribute__((ext_vector_type(2))) float f32x2;

#define MFMA16(a_, b_, c_) __builtin_amdgcn_mfma_f32_16x16x32_bf16((a_), (b_), (c_), 0, 0, 0)
#define GLLDS16(gp_, lp_) __builtin_amdgcn_global_load_lds( \
    (const __attribute__((address_space(1))) unsigned int*)(gp_), \
    (__attribute__((address_space(3))) unsigned int*)(lp_), 16, 0, 0)

__device__ __forceinline__ unsigned short f2bf(float f) {
  unsigned int u = __float_as_uint(f);
  u += 0x7fffu + ((u >> 16) & 1u);
  return (unsigned short)(u >> 16);
}
__device__ __forceinline__ float bf2f(unsigned short b) {
  return __uint_as_float(((unsigned int)b) << 16);
}

// ---------------- split x (elementwise, 8 elems/thread) ----------------
__global__ __launch_bounds__(256) void k_split_x(const float* __restrict__ x,
                                                 short* __restrict__ xhi,
                                                 short* __restrict__ xlo) {
  const size_t i = ((size_t)blockIdx.x * 256 + threadIdx.x) * 8;
  float4 a = *reinterpret_cast<const float4*>(&x[i]);
  float4 b = *reinterpret_cast<const float4*>(&x[i + 4]);
  float v[8] = {a.x, a.y, a.z, a.w, b.x, b.y, b.z, b.w};
  bf16x8 hi, lo;
#pragma unroll
  for (int j = 0; j < 8; ++j) {
    unsigned short h = f2bf(v[j]);
    hi[j] = (short)h;
    lo[j] = (short)f2bf(v[j] - bf2f(h));
  }
  *reinterpret_cast<bf16x8*>(&xhi[i]) = hi;
  *reinterpret_cast<bf16x8*>(&xlo[i]) = lo;
}

// ---------------- split + transpose weights: W[Kd][Nn] -> T[Nn][Kd] hi/lo ----------------
__global__ __launch_bounds__(256) void k_split_T(const float* __restrict__ W,
                                                 short* __restrict__ Thi,
                                                 short* __restrict__ Tlo,
                                                 int Kd, int Nn) {
  __shared__ float tile[32][33];
  const int k0 = blockIdx.y * 32, n0 = blockIdx.x * 32;
  const int t = threadIdx.x;
  const int r = t >> 3, cq = (t & 7) * 4;
  float4 v = *reinterpret_cast<const float4*>(&W[(size_t)(k0 + r) * Nn + n0 + cq]);
  tile[r][cq + 0] = v.x; tile[r][cq + 1] = v.y;
  tile[r][cq + 2] = v.z; tile[r][cq + 3] = v.w;
  __syncthreads();
  const int nrow = t >> 3, kq = (t & 7) * 4;
  s16x4 hi, lo;
#pragma unroll
  for (int i = 0; i < 4; ++i) {
    float f = tile[kq + i][nrow];
    unsigned short h = f2bf(f);
    hi[i] = (short)h;
    lo[i] = (short)f2bf(f - bf2f(h));
  }
  *reinterpret_cast<s16x4*>(&Thi[(size_t)(n0 + nrow) * Kd + k0 + kq]) = hi;
  *reinterpret_cast<s16x4*>(&Tlo[(size_t)(n0 + nrow) * Kd + k0 + kq]) = lo;
}

// ---------------- fold scale/riem into W_conv ----------------
__global__ __launch_bounds__(256) void k_fold(const float* __restrict__ Wc,
                                              const float* __restrict__ scale_p,
                                              const float* __restrict__ riem_p,
                                              float* __restrict__ Wfold) {
  const int t = threadIdx.x;
  const float scale = scale_p[0], riem = riem_p[0];
  for (int i = t; i < 288; i += 256)
    Wfold[i] = Wc[i] * (((i % 24) < 12) ? scale : riem);
}

// ---------------- split-bf16 MFMA GEMM, BM=128 BN=64 BK=32 (for proj) ----------------
__global__ __launch_bounds__(256) void k_gemm(const short* __restrict__ Ahi,
                                              const short* __restrict__ Alo,
                                              const short* __restrict__ Bhi,
                                              const short* __restrict__ Blo,
                                              const float* __restrict__ bias,
                                              float* __restrict__ Cout,
                                              int M, int Nn, int Kd) {
  __shared__ __align__(16) short sA[2][128 * 32];
  __shared__ __align__(16) short sB[2][64 * 32];
  const int tid = threadIdx.x;
  const int wv = tid >> 6, l = tid & 63;
  const int lr = l & 15, lg = l >> 4;
  const int row0 = blockIdx.y * 128;
  const int col0 = blockIdx.x * 64;
  const int wr = (wv >> 1) * 64;
  const int wc = (wv & 1) * 32;
  const int ar = tid >> 2, ac = tid & 3;
  f32x4 acc[4][2];
#pragma unroll
  for (int i = 0; i < 4; ++i)
#pragma unroll
    for (int j = 0; j < 2; ++j) acc[i][j] = (f32x4){0.f, 0.f, 0.f, 0.f};

  for (int k0 = 0; k0 < Kd; k0 += 32) {
#pragma unroll
    for (int j = 0; j < 2; ++j) {
      const int row = j * 64 + ar;
      const int cc = ac ^ ((row >> 1) & 3);
      const size_t so = (size_t)(row0 + row) * Kd + k0 + cc * 8;
      GLLDS16(Ahi + so, &sA[0][(j * 256 + (wv << 6)) * 8]);
      GLLDS16(Alo + so, &sA[1][(j * 256 + (wv << 6)) * 8]);
    }
    {
      const int row = ar;
      const int cc = ac ^ ((row >> 1) & 3);
      const size_t so = (size_t)(col0 + row) * Kd + k0 + cc * 8;
      GLLDS16(Bhi + so, &sB[0][(wv << 6) * 8]);
      GLLDS16(Blo + so, &sB[1][(wv << 6) * 8]);
    }
    __syncthreads();
    bf16x8 afh[4], afl[4], bfh[2], bfl[2];
#pragma unroll
    for (int ti = 0; ti < 4; ++ti) {
      const int row = wr + ti * 16 + lr;
      const int pc = lg ^ ((row >> 1) & 3);
      afh[ti] = *reinterpret_cast<const bf16x8*>(&sA[0][row * 32 + pc * 8]);
      afl[ti] = *reinterpret_cast<const bf16x8*>(&sA[1][row * 32 + pc * 8]);
    }
#pragma unroll
    for (int tj = 0; tj < 2; ++tj) {
      const int row = wc + tj * 16 + lr;
      const int pc = lg ^ ((row >> 1) & 3);
      bfh[tj] = *reinterpret_cast<const bf16x8*>(&sB[0][row * 32 + pc * 8]);
      bfl[tj] = *reinterpret_cast<const bf16x8*>(&sB[1][row * 32 + pc * 8]);
    }
#pragma unroll
    for (int ti = 0; ti < 4; ++ti)
#pragma unroll
      for (int tj = 0; tj < 2; ++tj) {
        acc[ti][tj] = MFMA16(afh[ti], bfh[tj], acc[ti][tj]);
        acc[ti][tj] = MFMA16(afl[ti], bfh[tj], acc[ti][tj]);
        acc[ti][tj] = MFMA16(afh[ti], bfl[tj], acc[ti][tj]);
      }
    __syncthreads();
  }
#pragma unroll
  for (int ti = 0; ti < 4; ++ti)
#pragma unroll
    for (int tj = 0; tj < 2; ++tj) {
      const int col = col0 + wc + tj * 16 + lr;
      const float bb = bias[col];
#pragma unroll
      for (int r = 0; r < 4; ++r) {
        const int row = row0 + wr + ti * 16 + lg * 4 + r;
        Cout[(size_t)row * Nn + col] = acc[ti][tj][r] + bb;
      }
    }
}

// ---------------- split-bf16 MFMA GEMM, BM=128 BN=128 BK=32 (for qkv) ----------------
__global__ __launch_bounds__(256) void k_gemm128(const short* __restrict__ Ahi,
                                                 const short* __restrict__ Alo,
                                                 const short* __restrict__ Bhi,
                                                 const short* __restrict__ Blo,
                                                 const float* __restrict__ bias,
                                                 float* __restrict__ Cout,
                                                 int M, int Nn, int Kd) {
  __shared__ __align__(16) short sA[2][128 * 32];
  __shared__ __align__(16) short sB[2][128 * 32];
  const int tid = threadIdx.x;
  const int wv = tid >> 6, l = tid & 63;
  const int lr = l & 15, lg = l >> 4;
  const int row0 = blockIdx.y * 128;
  const int col0 = blockIdx.x * 128;
  const int wr = (wv >> 1) * 64;
  const int wc = (wv & 1) * 64;
  const int ar = tid >> 2, ac = tid & 3;
  f32x4 acc[4][4];
#pragma unroll
  for (int i = 0; i < 4; ++i)
#pragma unroll
    for (int j = 0; j < 4; ++j) acc[i][j] = (f32x4){0.f, 0.f, 0.f, 0.f};

  for (int k0 = 0; k0 < Kd; k0 += 32) {
#pragma unroll
    for (int j = 0; j < 2; ++j) {
      const int row = j * 64 + ar;
      const int cc = ac ^ ((row >> 1) & 3);
      const size_t ao = (size_t)(row0 + row) * Kd + k0 + cc * 8;
      const size_t bo = (size_t)(col0 + row) * Kd + k0 + cc * 8;
      GLLDS16(Ahi + ao, &sA[0][(j * 256 + (wv << 6)) * 8]);
      GLLDS16(Alo + ao, &sA[1][(j * 256 + (wv << 6)) * 8]);
      GLLDS16(Bhi + bo, &sB[0][(j * 256 + (wv << 6)) * 8]);
      GLLDS16(Blo + bo, &sB[1][(j * 256 + (wv << 6)) * 8]);
    }
    __syncthreads();
    bf16x8 afh[4], afl[4], bfh[4], bfl[4];
#pragma unroll
    for (int ti = 0; ti < 4; ++ti) {
      const int row = wr + ti * 16 + lr;
      const int pc = lg ^ ((row >> 1) & 3);
      afh[ti] = *reinterpret_cast<const bf16x8*>(&sA[0][row * 32 + pc * 8]);
      afl[ti] = *reinterpret_cast<const bf16x8*>(&sA[1][row * 32 + pc * 8]);
    }
#pragma unroll
    for (int tj = 0; tj < 4; ++tj) {
      const int row = wc + tj * 16 + lr;
      const int pc = lg ^ ((row >> 1) & 3);
      bfh[tj] = *reinterpret_cast<const bf16x8*>(&sB[0][row * 32 + pc * 8]);
      bfl[tj] = *reinterpret_cast<const bf16x8*>(&sB[1][row * 32 + pc * 8]);
    }
#pragma unroll
    for (int ti = 0; ti < 4; ++ti)
#pragma unroll
      for (int tj = 0; tj < 4; ++tj) {
        acc[ti][tj] = MFMA16(afh[ti], bfh[tj], acc[ti][tj]);
        acc[ti][tj] = MFMA16(afl[ti], bfh[tj], acc[ti][tj]);
        acc[ti][tj] = MFMA16(afh[ti], bfl[tj], acc[ti][tj]);
      }
    __syncthreads();
  }
#pragma unroll
  for (int ti = 0; ti < 4; ++ti)
#pragma unroll
    for (int tj = 0; tj < 4; ++tj) {
      const int col = col0 + wc + tj * 16 + lr;
      const float bb = bias[col];
#pragma unroll
      for (int r = 0; r < 4; ++r) {
        const int row = row0 + wr + ti * 16 + lg * 4 + r;
        Cout[(size_t)row * Nn + col] = acc[ti][tj][r] + bb;
      }
    }
}

// ---------------- qkv post: split Q, center+split K, means, transpose V (single bf16) ----------------
__global__ __launch_bounds__(256) void k_qkv_post(const float* __restrict__ qkvf,
                                                  short* __restrict__ Qhi, short* __restrict__ Qlo,
                                                  short* __restrict__ KChi, short* __restrict__ KClo,
                                                  short* __restrict__ Vt,
                                                  float* __restrict__ Qm, float* __restrict__ Km) {
  __shared__ unsigned short lvh[64][33];
  const int b = blockIdx.z, h = blockIdx.y, n0 = blockIdx.x * 32;
  const int t = threadIdx.x;
  const int row = t >> 3, d0 = (t & 7) * 8;
  const int n = n0 + row;
  const float* base = qkvf + ((size_t)(b * 1024 + n)) * 2304 + h * 64 + d0;
  const size_t qko = ((size_t)(b * H_ + h) * N_ + n) * D_ + d0;

#pragma unroll
  for (int part = 0; part < 2; ++part) {  // 0: q, 1: k (centered)
    float4 a = *reinterpret_cast<const float4*>(base + part * 768);
    float4 c = *reinterpret_cast<const float4*>(base + part * 768 + 4);
    float v[8] = {a.x, a.y, a.z, a.w, c.x, c.y, c.z, c.w};
    float s = v[0] + v[1] + v[2] + v[3] + v[4] + v[5] + v[6] + v[7];
#pragma unroll
    for (int off = 1; off < 8; off <<= 1) s += __shfl_xor(s, off);
    const float mean = s * (1.0f / 64.0f);
    if ((t & 7) == 0) (part ? Km : Qm)[(size_t)(b * H_ + h) * N_ + n] = mean;
    const float sub = part ? mean : 0.0f;
    bf16x8 hi, lo;
#pragma unroll
    for (int j = 0; j < 8; ++j) {
      const float f = v[j] - sub;
      unsigned short hh = f2bf(f);
      hi[j] = (short)hh;
      lo[j] = (short)f2bf(f - bf2f(hh));
    }
    *reinterpret_cast<bf16x8*>((part ? KChi : Qhi) + qko) = hi;
    *reinterpret_cast<bf16x8*>((part ? KClo : Qlo) + qko) = lo;
  }
  {  // v -> transposed single bf16
    float4 a = *reinterpret_cast<const float4*>(base + 1536);
    float4 c = *reinterpret_cast<const float4*>(base + 1536 + 4);
    float v[8] = {a.x, a.y, a.z, a.w, c.x, c.y, c.z, c.w};
#pragma unroll
    for (int j = 0; j < 8; ++j) lvh[d0 + j][row] = f2bf(v[j]);
  }
  __syncthreads();
  const int d = t >> 2, c = t & 3;
  bf16x8 vh;
#pragma unroll
  for (int i = 0; i < 8; ++i) vh[i] = (short)lvh[d][c * 8 + i];
  const size_t vo = ((size_t)(b * H_ + h) * D_ + d) * N_ + n0 + c * 8;
  *reinterpret_cast<bf16x8*>(Vt + vo) = vh;
}

// ---------------- scores + channel mix -> logits (+ per-block softmax stats) ----------------
// 64n x 32m block (R13, best measured 148us). Each wave owns 16n x 32m.
__global__ __launch_bounds__(256, 2) void k_scores(
    const short* __restrict__ Qhi, const short* __restrict__ Qlo,
    const short* __restrict__ KChi, const short* __restrict__ KClo,
    const float* __restrict__ Qm, const float* __restrict__ Km,
    const float* __restrict__ Wfold, float* __restrict__ logits,
    float2* __restrict__ stats) {
  __shared__ __align__(16) short sCh[2][32 * 64];
  __shared__ __align__(16) short sCl[2][32 * 64];
  __shared__ float sQm[12][64];
  __shared__ float sKm[12][32];

  const int t = threadIdx.x;
  const int b = blockIdx.z;
  const int n0 = blockIdx.y * 64, m0 = blockIdx.x * 32;
  const int wv = t >> 6, l = t & 63;
  const int lr = l & 15, lg = l >> 4;
  const size_t bh0 = (size_t)b * H_;

  for (int i = t; i < 768; i += 256)
    sQm[i >> 6][i & 63] = Qm[(bh0 + (i >> 6)) * N_ + n0 + (i & 63)];
  for (int i = t; i < 384; i += 256)
    sKm[i >> 5][i & 31] = Km[(bh0 + (i >> 5)) * N_ + m0 + (i & 31)];

  const int srow = t >> 3;
  const int scs = (t & 7) ^ (srow & 7);
  const size_t csrc = (bh0 * N_ + m0 + srow) * D_ + scs * 8;
  const size_t hstep = (size_t)N_ * D_;
  const int nb = n0 + wv * 16;
  const size_t qsrc = (bh0 * N_ + nb + lr) * D_ + lg * 8;

  GLLDS16(KChi + csrc, &sCh[0][wv * 512]);
  GLLDS16(KClo + csrc, &sCl[0][wv * 512]);
  bf16x8 qh0 = *reinterpret_cast<const bf16x8*>(Qhi + qsrc);
  bf16x8 qh1 = *reinterpret_cast<const bf16x8*>(Qhi + qsrc + 32);
  bf16x8 ql0 = *reinterpret_cast<const bf16x8*>(Qlo + qsrc);
  bf16x8 ql1 = *reinterpret_cast<const bf16x8*>(Qlo + qsrc + 32);

  f32x2 aA01[12], aA23[12], aB01[12], aB23[12];
#pragma unroll
  for (int o = 0; o < 12; ++o) {
    aA01[o] = (f32x2){0.f, 0.f}; aA23[o] = (f32x2){0.f, 0.f};
    aB01[o] = (f32x2){0.f, 0.f}; aB23[o] = (f32x2){0.f, 0.f};
  }

  const int browA = lr, browB = 16 + lr;
  const int aiA0 = browA * 64 + ((lg + 0) ^ (browA & 7)) * 8;
  const int aiA1 = browA * 64 + ((lg + 4) ^ (browA & 7)) * 8;
  const int aiB0 = browB * 64 + ((lg + 0) ^ (browB & 7)) * 8;
  const int aiB1 = browB * 64 + ((lg + 4) ^ (browB & 7)) * 8;
  __syncthreads();

  int buf = 0;
#pragma unroll 2
  for (int h = 0; h < H_; ++h) {
    bf16x8 nqh0, nqh1, nql0, nql1;
    if (h < 11) {
      const size_t cs = csrc + (size_t)(h + 1) * hstep;
      GLLDS16(KChi + cs, &sCh[buf ^ 1][wv * 512]);
      GLLDS16(KClo + cs, &sCl[buf ^ 1][wv * 512]);
      const size_t qs = qsrc + (size_t)(h + 1) * hstep;
      nqh0 = *reinterpret_cast<const bf16x8*>(Qhi + qs);
      nqh1 = *reinterpret_cast<const bf16x8*>(Qhi + qs + 32);
      nql0 = *reinterpret_cast<const bf16x8*>(Qlo + qs);
      nql1 = *reinterpret_cast<const bf16x8*>(Qlo + qs + 32);
    }
    const bf16x8 chA0 = *reinterpret_cast<const bf16x8*>(&sCh[buf][aiA0]);
    const bf16x8 chA1 = *reinterpret_cast<const bf16x8*>(&sCh[buf][aiA1]);
    const bf16x8 clA0 = *reinterpret_cast<const bf16x8*>(&sCl[buf][aiA0]);
    const bf16x8 clA1 = *reinterpret_cast<const bf16x8*>(&sCl[buf][aiA1]);
    const bf16x8 chB0 = *reinterpret_cast<const bf16x8*>(&sCh[buf][aiB0]);
    const bf16x8 chB1 = *reinterpret_cast<const bf16x8*>(&sCh[buf][aiB1]);
    const bf16x8 clB0 = *reinterpret_cast<const bf16x8*>(&sCl[buf][aiB0]);
    const bf16x8 clB1 = *reinterpret_cast<const bf16x8*>(&sCl[buf][aiB1]);

    f32x4 uaA = {0.f, 0.f, 0.f, 0.f}, ubA = {0.f, 0.f, 0.f, 0.f};
    f32x4 uaB = {0.f, 0.f, 0.f, 0.f}, ubB = {0.f, 0.f, 0.f, 0.f};
    uaA = MFMA16(qh0, chA0, uaA);  ubA = MFMA16(qh1, chA1, ubA);
    uaB = MFMA16(qh0, chB0, uaB);  ubB = MFMA16(qh1, chB1, ubB);
    uaA = MFMA16(qh0, clA0, uaA);  ubA = MFMA16(qh1, clA1, ubA);
    uaB = MFMA16(qh0, clB0, uaB);  ubB = MFMA16(qh1, clB1, ubB);
    uaA = MFMA16(ql0, chA0, uaA);  ubA = MFMA16(ql1, chA1, ubA);
    uaB = MFMA16(ql0, chB0, uaB);  ubB = MFMA16(ql1, chB1, ubB);

    const float4 qm4 = *reinterpret_cast<const float4*>(&sQm[h][wv * 16 + lg * 4]);
    const float kmA = 64.0f * sKm[h][lr];
    const float kmB = 64.0f * sKm[h][16 + lr];
    const f32x2 qm01 = {qm4.x, qm4.y};
    const f32x2 qm23 = {qm4.z, qm4.w};
    const f32x2 uA01 = {uaA[0] + ubA[0], uaA[1] + ubA[1]};
    const f32x2 uA23 = {uaA[2] + ubA[2], uaA[3] + ubA[3]};
    const f32x2 uB01 = {uaB[0] + ubB[0], uaB[1] + ubB[1]};
    const f32x2 uB23 = {uaB[2] + ubB[2], uaB[3] + ubB[3]};
    const f32x2 svA01 = kmA * qm01 + uA01;
    const f32x2 svA23 = kmA * qm23 + uA23;
    const f32x2 svB01 = kmB * qm01 + uB01;
    const f32x2 svB23 = kmB * qm23 + uB23;
    const f32x2 u2A01 = uA01 * uA01;
    const f32x2 u2A23 = uA23 * uA23;
    const f32x2 u2B01 = uB01 * uB01;
    const f32x2 u2B23 = uB23 * uB23;
#pragma unroll
    for (int o = 0; o < 12; ++o) {
      const float we = Wfold[o * 24 + h];
      const float wr = Wfold[o * 24 + 12 + h];
      aA01[o] = aA01[o] + we * svA01 + wr * u2A01;
      aA23[o] = aA23[o] + we * svA23 + wr * u2A23;
      aB01[o] = aB01[o] + we * svB01 + wr * u2B01;
      aB23[o] = aB23[o] + we * svB23 + wr * u2B23;
    }
    __syncthreads();
    buf ^= 1;
    if (h < 11) { qh0 = nqh0; qh1 = nqh1; ql0 = nql0; ql1 = nql1; }
  }

#pragma unroll
  for (int o = 0; o < 12; ++o) {
    float* dst = &logits[((bh0 + o) * N_ + nb) * N_ + m0 + lr];
    dst[(size_t)(lg * 4 + 0) * N_] = aA01[o][0];
    dst[(size_t)(lg * 4 + 1) * N_] = aA01[o][1];
    dst[(size_t)(lg * 4 + 2) * N_] = aA23[o][0];
    dst[(size_t)(lg * 4 + 3) * N_] = aA23[o][1];
    dst[(size_t)(lg * 4 + 0) * N_ + 16] = aB01[o][0];
    dst[(size_t)(lg * 4 + 1) * N_ + 16] = aB01[o][1];
    dst[(size_t)(lg * 4 + 2) * N_ + 16] = aB23[o][0];
    dst[(size_t)(lg * 4 + 3) * N_ + 16] = aB23[o][1];
  }
#pragma unroll
  for (int o = 0; o < 12; ++o) {
    float avA[4] = {aA01[o][0], aA01[o][1], aA23[o][0], aA23[o][1]};
    float avB[4] = {aB01[o][0], aB01[o][1], aB23[o][0], aB23[o][1]};
    float M4[4], S4[4];
#pragma unroll
    for (int r = 0; r < 4; ++r) {
      float mxA = avA[r], mxB = avB[r];
      mxA = fmaxf(mxA, __shfl_xor(mxA, 1)); mxB = fmaxf(mxB, __shfl_xor(mxB, 1));
      mxA = fmaxf(mxA, __shfl_xor(mxA, 2)); mxB = fmaxf(mxB, __shfl_xor(mxB, 2));
      mxA = fmaxf(mxA, __shfl_xor(mxA, 4)); mxB = fmaxf(mxB, __shfl_xor(mxB, 4));
      mxA = fmaxf(mxA, __shfl_xor(mxA, 8)); mxB = fmaxf(mxB, __shfl_xor(mxB, 8));
      const float M = fmaxf(mxA, mxB);
      float eA = __expf(avA[r] - M);
      float eB = __expf(avB[r] - M);
      float e = eA + eB;
      e += __shfl_xor(e, 1);
      e += __shfl_xor(e, 2);
      e += __shfl_xor(e, 4);
      e += __shfl_xor(e, 8);
      M4[r] = M; S4[r] = e;
    }
    if (lr < 4) {
      const int n = nb + lg * 4 + lr;
      stats[(((size_t)b * 12 + o) * 32 + blockIdx.x) * 1024 + n] = make_float2(M4[lr], S4[lr]);
    }
  }
}

// ---------------- merge partial stats -> per-row (M, 1/S) ----------------
__global__ __launch_bounds__(256) void k_merge(const float2* __restrict__ stats,
                                               float2* __restrict__ merged) {
  const int bo = blockIdx.y;
  const int n = blockIdx.x * 256 + threadIdx.x;
  float M = -3.0e38f, S = 0.f;
  for (int seg = 0; seg < 32; ++seg) {
    const float2 p = stats[((size_t)bo * 32 + seg) * 1024 + n];
    if (p.x > M) {
      S = S * __expf(M - p.x) + p.y;
      M = p.x;
    } else {
      S += p.y * __expf(p.x - M);
    }
  }
  merged[(size_t)bo * 1024 + n] = make_float2(M, 1.0f / S);
}

// ---------------- fused softmax + attn-write + PV MFMA (128n x 64m chunks, bf16 V dbuf) ----------------
// n-tile 64->128: V re-read redundancy halves again; 2x MFMA+softmax per barrier.
// Wave wv owns rows [wv*32, wv*32+32) x all 64 d (2 n-subtiles x 4 d-tiles).
__global__ __launch_bounds__(256) void k_pvsm(float* __restrict__ attn,
                                              const float2* __restrict__ merged,
                                              const short* __restrict__ Vt,
                                              short* __restrict__ ohi,
                                              short* __restrict__ olo) {
  __shared__ __align__(16) short sPhi[128 * 64];
  __shared__ __align__(16) short sPlo[128 * 64];
  __shared__ __align__(16) short sV[2][64 * 64];
  __shared__ float sM[128], sIS[128];
  const int b = blockIdx.z, o = blockIdx.y;
  const int n0 = blockIdx.x * 128;
  const int bo = b * H_ + o;
  const int t = threadIdx.x;
  const int wv = t >> 6, l = t & 63;
  const int lr = l & 15, lg = l >> 4;
  const int nsub = wv * 32;

  const int vr0 = t >> 3, vr1 = vr0 + 32;
  const int vc0 = (t & 7) ^ (vr0 & 7);
  const int vc1 = (t & 7) ^ (vr1 & 7);
  const size_t vbase = (size_t)bo * D_ * N_;
  const size_t vs0 = vbase + (size_t)vr0 * N_ + vc0 * 8;
  const size_t vs1 = vbase + (size_t)vr1 * N_ + vc1 * 8;

  if (t < 128) {
    const float2 ms = merged[(size_t)bo * 1024 + n0 + t];
    sM[t] = ms.x;
    sIS[t] = ms.y;
  }
  GLLDS16(Vt + vs0, &sV[0][(wv * 64) * 8]);
  GLLDS16(Vt + vs1, &sV[0][(wv * 64 + 256) * 8]);

  // P softmax: each thread handles rows prow+{0,32,64,96}, 8 cols at c0
  const int prow = t >> 3, c0 = (t & 7) * 8;
  const int pxor = ((t & 7) ^ (prow & 7)) * 8;  // (prow+32k)&7 == prow&7
  float* lrow0 = attn + ((size_t)bo * N_ + n0 + prow) * N_;
  float* lrow1 = lrow0 + (size_t)32 * N_;
  float* lrow2 = lrow0 + (size_t)64 * N_;
  float* lrow3 = lrow0 + (size_t)96 * N_;
  const int pofs0 = prow * 64 + pxor;
  const int pofs1 = pofs0 + 32 * 64;
  const int pofs2 = pofs0 + 64 * 64;
  const int pofs3 = pofs0 + 96 * 64;

  // A-frag (P) addrs: rows nsub + ns*16 + lr
  const int arow0 = nsub + lr, arow1 = nsub + 16 + lr;
  const int a00 = arow0 * 64 + (((lg + 0) ^ (arow0 & 7)) * 8);
  const int a01 = arow0 * 64 + (((lg + 4) ^ (arow0 & 7)) * 8);
  const int a10 = arow1 * 64 + (((lg + 0) ^ (arow1 & 7)) * 8);
  const int a11 = arow1 * 64 + (((lg + 4) ^ (arow1 & 7)) * 8);

  f32x4 acc[2][4];
#pragma unroll
  for (int ns = 0; ns < 2; ++ns)
#pragma unroll
    for (int dt = 0; dt < 4; ++dt) acc[ns][dt] = (f32x4){0.f, 0.f, 0.f, 0.f};
  __syncthreads();

  for (int mc = 0; mc < 16; ++mc) {
    const int m0 = mc * 64;
    if (mc < 15) {  // prefetch next V chunk (lands during softmax phase)
      const int nb2 = (mc + 1) & 1;
      GLLDS16(Vt + vs0 + m0 + 64, &sV[nb2][(wv * 64) * 8]);
      GLLDS16(Vt + vs1 + m0 + 64, &sV[nb2][(wv * 64 + 256) * 8]);
    }
    // softmax-normalize 4 rows x 8 cols, write attn in-place, pack split-bf16 P
    float* lrows[4] = {lrow0, lrow1, lrow2, lrow3};
    const int pofs[4] = {pofs0, pofs1, pofs2, pofs3};
#pragma unroll
    for (int k = 0; k < 4; ++k) {
      const float Mr = sM[prow + k * 32], iS = sIS[prow + k * 32];
      float4 la = *reinterpret_cast<const float4*>(&lrows[k][m0 + c0]);
      float4 lb = *reinterpret_cast<const float4*>(&lrows[k][m0 + c0 + 4]);
      float p[8];
      p[0] = __expf(la.x - Mr) * iS; p[1] = __expf(la.y - Mr) * iS;
      p[2] = __expf(la.z - Mr) * iS; p[3] = __expf(la.w - Mr) * iS;
      p[4] = __expf(lb.x - Mr) * iS; p[5] = __expf(lb.y - Mr) * iS;
      p[6] = __expf(lb.z - Mr) * iS; p[7] = __expf(lb.w - Mr) * iS;
      float4 oa = {p[0], p[1], p[2], p[3]};
      float4 ob = {p[4], p[5], p[6], p[7]};
      *reinterpret_cast<float4*>(&lrows[k][m0 + c0]) = oa;
      *reinterpret_cast<float4*>(&lrows[k][m0 + c0 + 4]) = ob;
      bf16x8 phi, plo;
#pragma unroll
      for (int j = 0; j < 8; ++j) {
        unsigned short hh = f2bf(p[j]);
        phi[j] = (short)hh;
        plo[j] = (short)f2bf(p[j] - bf2f(hh));
      }
      *reinterpret_cast<bf16x8*>(&sPhi[pofs[k]]) = phi;
      *reinterpret_cast<bf16x8*>(&sPlo[pofs[k]]) = plo;
    }
    __syncthreads();  // P ready; V[cur] (issued last iter) drained

    const int cur = mc & 1;
    const bf16x8 pA0h = *reinterpret_cast<const bf16x8*>(&sPhi[a00]);
    const bf16x8 pA1h = *reinterpret_cast<const bf16x8*>(&sPhi[a01]);
    const bf16x8 pA0l = *reinterpret_cast<const bf16x8*>(&sPlo[a00]);
    const bf16x8 pA1l = *reinterpret_cast<const bf16x8*>(&sPlo[a01]);
    const bf16x8 pB0h = *reinterpret_cast<const bf16x8*>(&sPhi[a10]);
    const bf16x8 pB1h = *reinterpret_cast<const bf16x8*>(&sPhi[a11]);
    const bf16x8 pB0l = *reinterpret_cast<const bf16x8*>(&sPlo[a10]);
    const bf16x8 pB1l = *reinterpret_cast<const bf16x8*>(&sPlo[a11]);
#pragma unroll
    for (int dt = 0; dt < 4; ++dt) {
      const int drow = dt * 16 + lr;
      const bf16x8 vh0 = *reinterpret_cast<const bf16x8*>(&sV[cur][drow * 64 + (((lg + 0) ^ (drow & 7)) * 8)]);
      const bf16x8 vh1 = *reinterpret_cast<const bf16x8*>(&sV[cur][drow * 64 + (((lg + 4) ^ (drow & 7)) * 8)]);
      acc[0][dt] = MFMA16(pA0h, vh0, acc[0][dt]);
      acc[0][dt] = MFMA16(pA0l, vh0, acc[0][dt]);
      acc[0][dt] = MFMA16(pA1h, vh1, acc[0][dt]);
      acc[0][dt] = MFMA16(pA1l, vh1, acc[0][dt]);
      acc[1][dt] = MFMA16(pB0h, vh0, acc[1][dt]);
      acc[1][dt] = MFMA16(pB0l, vh0, acc[1][dt]);
      acc[1][dt] = MFMA16(pB1h, vh1, acc[1][dt]);
      acc[1][dt] = MFMA16(pB1l, vh1, acc[1][dt]);
    }
    __syncthreads();  // protect sP/sV reuse
  }
  // epilogue: wave owns 32 n x 64 d
#pragma unroll
  for (int ns = 0; ns < 2; ++ns)
#pragma unroll
    for (int dt = 0; dt < 4; ++dt) {
      const int d = dt * 16 + lr;
#pragma unroll
      for (int r = 0; r < 4; ++r) {
        const int n = n0 + nsub + ns * 16 + lg * 4 + r;
        const float val = acc[ns][dt][r];
        const unsigned short hh = f2bf(val);
        const size_t oo = (size_t)(b * 1024 + n) * 768 + o * 64 + d;
        ohi[oo] = (short)hh;
        olo[oo] = (short)f2bf(val - bf2f(hh));
      }
    }
}

extern "C" void kernel_launch(void* const* d_in, const int* in_sizes, int n_in,
                              void* d_out, int out_size, void* d_ws, size_t ws_size,
                              hipStream_t stream) {
  (void)in_sizes; (void)n_in; (void)out_size; (void)ws_size;
  const float* x      = (const float*)d_in[0];
  const float* W_qkv  = (const float*)d_in[1];
  const float* b_qkv  = (const float*)d_in[2];
  const float* scale  = (const float*)d_in[3];
  const float* riem   = (const float*)d_in[4];
  const float* W_conv = (const float*)d_in[5];
  // d_in[6] = b_conv: constant along softmax axis -> softmax-invariant, skipped
  const float* W_proj = (const float*)d_in[7];
  const float* b_proj = (const float*)d_in[8];

  float* out_final = (float*)d_out;                     // [B,N,C]
  float* attn_out  = out_final + (size_t)B_ * N_ * C_;  // [B,H,N,N] logits -> attn in-place

  char* w = (char*)d_ws;
  short* xhi  = (short*)w;                       // 6291456 B
  short* xlo  = xhi + 3145728;                   // 6291456 B
  short* Wthi = (short*)(w + 12582912);          // 3538944 B
  short* Wtlo = Wthi + 1769472;                  // 3538944 B
  short* Wpthi = (short*)(w + 19660800);         // 1179648 B
  short* Wptlo = Wpthi + 589824;                 // 1179648 B
  float* qkvf = (float*)(w + 22020096);          // 37748736 B
  short* Qhi  = (short*)(w + 59768832);
  short* Qlo  = Qhi + 3145728;
  short* KChi = Qlo + 3145728;
  short* KClo = KChi + 3145728;                  // ws end: 84934656 B
  // aliases (lifetime-disjoint)
  short* Vt = xhi;                               // after k_gemm128(qkv), x splits dead (single bf16)
  float* Wfold = (float*)Wthi;                   // Wt dead after qkv gemm (1152 B)
  float* Qm = (float*)((char*)Wthi + 8192);      // 196608 B
  float* Km = (float*)((char*)Wthi + 8192 + 196608);
  float2* stats  = (float2*)((char*)qkvf + 12582912);
  float2* merged = (float2*)((char*)qkvf + 25165824);
  short* ohi = Qhi;                              // after k_scores, Q splits dead
  short* olo = Qlo;

  k_split_x<<<dim3(1536), 256, 0, stream>>>(x, xhi, xlo);
  k_split_T<<<dim3(72, 24), 256, 0, stream>>>(W_qkv, Wthi, Wtlo, 768, 2304);
  k_split_T<<<dim3(24, 24), 256, 0, stream>>>(W_proj, Wpthi, Wptlo, 768, 768);
  k_gemm128<<<dim3(18, 32), 256, 0, stream>>>(xhi, xlo, Wthi, Wtlo, b_qkv, qkvf, 4096, 2304, 768);
  k_fold<<<dim3(1), 256, 0, stream>>>(W_conv, scale, riem, Wfold);
  k_qkv_post<<<dim3(32, 12, 4), 256, 0, stream>>>(qkvf, Qhi, Qlo, KChi, KClo, Vt, Qm, Km);
  k_scores<<<dim3(32, 16, 4), 256, 0, stream>>>(Qhi, Qlo, KChi, KClo, Qm, Km, Wfold, attn_out, stats);
  k_merge<<<dim3(4, 48), 256, 0, stream>>>(stats, merged);
  k_pvsm<<<dim3(8, 12, 4), 256, 0, stream>>>(attn_out, merged, Vt, ohi, olo);
  k_gemm<<<dim3(12, 32), 256, 0, stream>>>(ohi, olo, Wpthi, Wptlo, b_proj, out_final, 4096, 768, 768);
}

// Round 15
// 357.334 us; speedup vs baseline: 1.0449x; 1.0449x over previous
//
#include <hip/hip_runtime.h>
#include <cstddef>
#include <cstdint>

#define B_ 4
#define N_ 1024
#define C_ 768
#define H_ 12
#define D_ 64

typedef __attribute__((ext_vector_type(8))) short bf16x8;
typedef __attribute__((ext_vector_type(4))) short s16x4;
typedef __attribute__((ext_vector_type(4))) float f32x4;
typedef __attribute__((ext_vector_type(2))) float f32x2;

#define MFMA16(a_, b_, c_) __builtin_amdgcn_mfma_f32_16x16x32_bf16((a_), (b_), (c_), 0, 0, 0)
#define GLLDS16(gp_, lp_) __builtin_amdgcn_global_load_lds( \
    (const __attribute__((address_space(1))) unsigned int*)(gp_), \
    (__attribute__((address_space(3))) unsigned int*)(lp_), 16, 0, 0)

__device__ __forceinline__ unsigned short f2bf(float f) {
  unsigned int u = __float_as_uint(f);
  u += 0x7fffu + ((u >> 16) & 1u);
  return (unsigned short)(u >> 16);
}
__device__ __forceinline__ float bf2f(unsigned short b) {
  return __uint_as_float(((unsigned int)b) << 16);
}

// ---------------- split x (elementwise, 8 elems/thread) ----------------
__global__ __launch_bounds__(256) void k_split_x(const float* __restrict__ x,
                                                 short* __restrict__ xhi,
                                                 short* __restrict__ xlo) {
  const size_t i = ((size_t)blockIdx.x * 256 + threadIdx.x) * 8;
  float4 a = *reinterpret_cast<const float4*>(&x[i]);
  float4 b = *reinterpret_cast<const float4*>(&x[i + 4]);
  float v[8] = {a.x, a.y, a.z, a.w, b.x, b.y, b.z, b.w};
  bf16x8 hi, lo;
#pragma unroll
  for (int j = 0; j < 8; ++j) {
    unsigned short h = f2bf(v[j]);
    hi[j] = (short)h;
    lo[j] = (short)f2bf(v[j] - bf2f(h));
  }
  *reinterpret_cast<bf16x8*>(&xhi[i]) = hi;
  *reinterpret_cast<bf16x8*>(&xlo[i]) = lo;
}

// ---------------- split + transpose weights: W[Kd][Nn] -> T[Nn][Kd] hi/lo ----------------
__global__ __launch_bounds__(256) void k_split_T(const float* __restrict__ W,
                                                 short* __restrict__ Thi,
                                                 short* __restrict__ Tlo,
                                                 int Kd, int Nn) {
  __shared__ float tile[32][33];
  const int k0 = blockIdx.y * 32, n0 = blockIdx.x * 32;
  const int t = threadIdx.x;
  const int r = t >> 3, cq = (t & 7) * 4;
  float4 v = *reinterpret_cast<const float4*>(&W[(size_t)(k0 + r) * Nn + n0 + cq]);
  tile[r][cq + 0] = v.x; tile[r][cq + 1] = v.y;
  tile[r][cq + 2] = v.z; tile[r][cq + 3] = v.w;
  __syncthreads();
  const int nrow = t >> 3, kq = (t & 7) * 4;
  s16x4 hi, lo;
#pragma unroll
  for (int i = 0; i < 4; ++i) {
    float f = tile[kq + i][nrow];
    unsigned short h = f2bf(f);
    hi[i] = (short)h;
    lo[i] = (short)f2bf(f - bf2f(h));
  }
  *reinterpret_cast<s16x4*>(&Thi[(size_t)(n0 + nrow) * Kd + k0 + kq]) = hi;
  *reinterpret_cast<s16x4*>(&Tlo[(size_t)(n0 + nrow) * Kd + k0 + kq]) = lo;
}

// ---------------- fold scale/riem into W_conv ----------------
__global__ __launch_bounds__(256) void k_fold(const float* __restrict__ Wc,
                                              const float* __restrict__ scale_p,
                                              const float* __restrict__ riem_p,
                                              float* __restrict__ Wfold) {
  const int t = threadIdx.x;
  const float scale = scale_p[0], riem = riem_p[0];
  for (int i = t; i < 288; i += 256)
    Wfold[i] = Wc[i] * (((i % 24) < 12) ? scale : riem);
}

// ---------------- split-bf16 MFMA GEMM, BM=128 BN=64 BK=32 (for proj) ----------------
__global__ __launch_bounds__(256) void k_gemm(const short* __restrict__ Ahi,
                                              const short* __restrict__ Alo,
                                              const short* __restrict__ Bhi,
                                              const short* __restrict__ Blo,
                                              const float* __restrict__ bias,
                                              float* __restrict__ Cout,
                                              int M, int Nn, int Kd) {
  __shared__ __align__(16) short sA[2][128 * 32];
  __shared__ __align__(16) short sB[2][64 * 32];
  const int tid = threadIdx.x;
  const int wv = tid >> 6, l = tid & 63;
  const int lr = l & 15, lg = l >> 4;
  const int row0 = blockIdx.y * 128;
  const int col0 = blockIdx.x * 64;
  const int wr = (wv >> 1) * 64;
  const int wc = (wv & 1) * 32;
  const int ar = tid >> 2, ac = tid & 3;
  f32x4 acc[4][2];
#pragma unroll
  for (int i = 0; i < 4; ++i)
#pragma unroll
    for (int j = 0; j < 2; ++j) acc[i][j] = (f32x4){0.f, 0.f, 0.f, 0.f};

  for (int k0 = 0; k0 < Kd; k0 += 32) {
#pragma unroll
    for (int j = 0; j < 2; ++j) {
      const int row = j * 64 + ar;
      const int cc = ac ^ ((row >> 1) & 3);
      const size_t so = (size_t)(row0 + row) * Kd + k0 + cc * 8;
      GLLDS16(Ahi + so, &sA[0][(j * 256 + (wv << 6)) * 8]);
      GLLDS16(Alo + so, &sA[1][(j * 256 + (wv << 6)) * 8]);
    }
    {
      const int row = ar;
      const int cc = ac ^ ((row >> 1) & 3);
      const size_t so = (size_t)(col0 + row) * Kd + k0 + cc * 8;
      GLLDS16(Bhi + so, &sB[0][(wv << 6) * 8]);
      GLLDS16(Blo + so, &sB[1][(wv << 6) * 8]);
    }
    __syncthreads();
    bf16x8 afh[4], afl[4], bfh[2], bfl[2];
#pragma unroll
    for (int ti = 0; ti < 4; ++ti) {
      const int row = wr + ti * 16 + lr;
      const int pc = lg ^ ((row >> 1) & 3);
      afh[ti] = *reinterpret_cast<const bf16x8*>(&sA[0][row * 32 + pc * 8]);
      afl[ti] = *reinterpret_cast<const bf16x8*>(&sA[1][row * 32 + pc * 8]);
    }
#pragma unroll
    for (int tj = 0; tj < 2; ++tj) {
      const int row = wc + tj * 16 + lr;
      const int pc = lg ^ ((row >> 1) & 3);
      bfh[tj] = *reinterpret_cast<const bf16x8*>(&sB[0][row * 32 + pc * 8]);
      bfl[tj] = *reinterpret_cast<const bf16x8*>(&sB[1][row * 32 + pc * 8]);
    }
#pragma unroll
    for (int ti = 0; ti < 4; ++ti)
#pragma unroll
      for (int tj = 0; tj < 2; ++tj) {
        acc[ti][tj] = MFMA16(afh[ti], bfh[tj], acc[ti][tj]);
        acc[ti][tj] = MFMA16(afl[ti], bfh[tj], acc[ti][tj]);
        acc[ti][tj] = MFMA16(afh[ti], bfl[tj], acc[ti][tj]);
      }
    __syncthreads();
  }
#pragma unroll
  for (int ti = 0; ti < 4; ++ti)
#pragma unroll
    for (int tj = 0; tj < 2; ++tj) {
      const int col = col0 + wc + tj * 16 + lr;
      const float bb = bias[col];
#pragma unroll
      for (int r = 0; r < 4; ++r) {
        const int row = row0 + wr + ti * 16 + lg * 4 + r;
        Cout[(size_t)row * Nn + col] = acc[ti][tj][r] + bb;
      }
    }
}

// ---------------- split-bf16 MFMA GEMM, BM=128 BN=128 BK=32 (for qkv) ----------------
__global__ __launch_bounds__(256) void k_gemm128(const short* __restrict__ Ahi,
                                                 const short* __restrict__ Alo,
                                                 const short* __restrict__ Bhi,
                                                 const short* __restrict__ Blo,
                                                 const float* __restrict__ bias,
                                                 float* __restrict__ Cout,
                                                 int M, int Nn, int Kd) {
  __shared__ __align__(16) short sA[2][128 * 32];
  __shared__ __align__(16) short sB[2][128 * 32];
  const int tid = threadIdx.x;
  const int wv = tid >> 6, l = tid & 63;
  const int lr = l & 15, lg = l >> 4;
  const int row0 = blockIdx.y * 128;
  const int col0 = blockIdx.x * 128;
  const int wr = (wv >> 1) * 64;
  const int wc = (wv & 1) * 64;
  const int ar = tid >> 2, ac = tid & 3;
  f32x4 acc[4][4];
#pragma unroll
  for (int i = 0; i < 4; ++i)
#pragma unroll
    for (int j = 0; j < 4; ++j) acc[i][j] = (f32x4){0.f, 0.f, 0.f, 0.f};

  for (int k0 = 0; k0 < Kd; k0 += 32) {
#pragma unroll
    for (int j = 0; j < 2; ++j) {
      const int row = j * 64 + ar;
      const int cc = ac ^ ((row >> 1) & 3);
      const size_t ao = (size_t)(row0 + row) * Kd + k0 + cc * 8;
      const size_t bo = (size_t)(col0 + row) * Kd + k0 + cc * 8;
      GLLDS16(Ahi + ao, &sA[0][(j * 256 + (wv << 6)) * 8]);
      GLLDS16(Alo + ao, &sA[1][(j * 256 + (wv << 6)) * 8]);
      GLLDS16(Bhi + bo, &sB[0][(j * 256 + (wv << 6)) * 8]);
      GLLDS16(Blo + bo, &sB[1][(j * 256 + (wv << 6)) * 8]);
    }
    __syncthreads();
    bf16x8 afh[4], afl[4], bfh[4], bfl[4];
#pragma unroll
    for (int ti = 0; ti < 4; ++ti) {
      const int row = wr + ti * 16 + lr;
      const int pc = lg ^ ((row >> 1) & 3);
      afh[ti] = *reinterpret_cast<const bf16x8*>(&sA[0][row * 32 + pc * 8]);
      afl[ti] = *reinterpret_cast<const bf16x8*>(&sA[1][row * 32 + pc * 8]);
    }
#pragma unroll
    for (int tj = 0; tj < 4; ++tj) {
      const int row = wc + tj * 16 + lr;
      const int pc = lg ^ ((row >> 1) & 3);
      bfh[tj] = *reinterpret_cast<const bf16x8*>(&sB[0][row * 32 + pc * 8]);
      bfl[tj] = *reinterpret_cast<const bf16x8*>(&sB[1][row * 32 + pc * 8]);
    }
#pragma unroll
    for (int ti = 0; ti < 4; ++ti)
#pragma unroll
      for (int tj = 0; tj < 4; ++tj) {
        acc[ti][tj] = MFMA16(afh[ti], bfh[tj], acc[ti][tj]);
        acc[ti][tj] = MFMA16(afl[ti], bfh[tj], acc[ti][tj]);
        acc[ti][tj] = MFMA16(afh[ti], bfl[tj], acc[ti][tj]);
      }
    __syncthreads();
  }
#pragma unroll
  for (int ti = 0; ti < 4; ++ti)
#pragma unroll
    for (int tj = 0; tj < 4; ++tj) {
      const int col = col0 + wc + tj * 16 + lr;
      const float bb = bias[col];
#pragma unroll
      for (int r = 0; r < 4; ++r) {
        const int row = row0 + wr + ti * 16 + lg * 4 + r;
        Cout[(size_t)row * Nn + col] = acc[ti][tj][r] + bb;
      }
    }
}

// ---------------- qkv post: split Q, center+split K, means, transpose V (single bf16) ----------------
__global__ __launch_bounds__(256) void k_qkv_post(const float* __restrict__ qkvf,
                                                  short* __restrict__ Qhi, short* __restrict__ Qlo,
                                                  short* __restrict__ KChi, short* __restrict__ KClo,
                                                  short* __restrict__ Vt,
                                                  float* __restrict__ Qm, float* __restrict__ Km) {
  __shared__ unsigned short lvh[64][33];
  const int b = blockIdx.z, h = blockIdx.y, n0 = blockIdx.x * 32;
  const int t = threadIdx.x;
  const int row = t >> 3, d0 = (t & 7) * 8;
  const int n = n0 + row;
  const float* base = qkvf + ((size_t)(b * 1024 + n)) * 2304 + h * 64 + d0;
  const size_t qko = ((size_t)(b * H_ + h) * N_ + n) * D_ + d0;

#pragma unroll
  for (int part = 0; part < 2; ++part) {  // 0: q, 1: k (centered)
    float4 a = *reinterpret_cast<const float4*>(base + part * 768);
    float4 c = *reinterpret_cast<const float4*>(base + part * 768 + 4);
    float v[8] = {a.x, a.y, a.z, a.w, c.x, c.y, c.z, c.w};
    float s = v[0] + v[1] + v[2] + v[3] + v[4] + v[5] + v[6] + v[7];
#pragma unroll
    for (int off = 1; off < 8; off <<= 1) s += __shfl_xor(s, off);
    const float mean = s * (1.0f / 64.0f);
    if ((t & 7) == 0) (part ? Km : Qm)[(size_t)(b * H_ + h) * N_ + n] = mean;
    const float sub = part ? mean : 0.0f;
    bf16x8 hi, lo;
#pragma unroll
    for (int j = 0; j < 8; ++j) {
      const float f = v[j] - sub;
      unsigned short hh = f2bf(f);
      hi[j] = (short)hh;
      lo[j] = (short)f2bf(f - bf2f(hh));
    }
    *reinterpret_cast<bf16x8*>((part ? KChi : Qhi) + qko) = hi;
    *reinterpret_cast<bf16x8*>((part ? KClo : Qlo) + qko) = lo;
  }
  {  // v -> transposed single bf16
    float4 a = *reinterpret_cast<const float4*>(base + 1536);
    float4 c = *reinterpret_cast<const float4*>(base + 1536 + 4);
    float v[8] = {a.x, a.y, a.z, a.w, c.x, c.y, c.z, c.w};
#pragma unroll
    for (int j = 0; j < 8; ++j) lvh[d0 + j][row] = f2bf(v[j]);
  }
  __syncthreads();
  const int d = t >> 2, c = t & 3;
  bf16x8 vh;
#pragma unroll
  for (int i = 0; i < 8; ++i) vh[i] = (short)lvh[d][c * 8 + i];
  const size_t vo = ((size_t)(b * H_ + h) * D_ + d) * N_ + n0 + c * 8;
  *reinterpret_cast<bf16x8*>(Vt + vo) = vh;
}

// ---------------- scores + channel mix -> logits (+ per-block softmax stats) ----------------
// 64n x 32m block (R13, best measured 148us). Each wave owns 16n x 32m.
__global__ __launch_bounds__(256, 2) void k_scores(
    const short* __restrict__ Qhi, const short* __restrict__ Qlo,
    const short* __restrict__ KChi, const short* __restrict__ KClo,
    const float* __restrict__ Qm, const float* __restrict__ Km,
    const float* __restrict__ Wfold, float* __restrict__ logits,
    float2* __restrict__ stats) {
  __shared__ __align__(16) short sCh[2][32 * 64];
  __shared__ __align__(16) short sCl[2][32 * 64];
  __shared__ float sQm[12][64];
  __shared__ float sKm[12][32];

  const int t = threadIdx.x;
  const int b = blockIdx.z;
  const int n0 = blockIdx.y * 64, m0 = blockIdx.x * 32;
  const int wv = t >> 6, l = t & 63;
  const int lr = l & 15, lg = l >> 4;
  const size_t bh0 = (size_t)b * H_;

  for (int i = t; i < 768; i += 256)
    sQm[i >> 6][i & 63] = Qm[(bh0 + (i >> 6)) * N_ + n0 + (i & 63)];
  for (int i = t; i < 384; i += 256)
    sKm[i >> 5][i & 31] = Km[(bh0 + (i >> 5)) * N_ + m0 + (i & 31)];

  const int srow = t >> 3;
  const int scs = (t & 7) ^ (srow & 7);
  const size_t csrc = (bh0 * N_ + m0 + srow) * D_ + scs * 8;
  const size_t hstep = (size_t)N_ * D_;
  const int nb = n0 + wv * 16;
  const size_t qsrc = (bh0 * N_ + nb + lr) * D_ + lg * 8;

  GLLDS16(KChi + csrc, &sCh[0][wv * 512]);
  GLLDS16(KClo + csrc, &sCl[0][wv * 512]);
  bf16x8 qh0 = *reinterpret_cast<const bf16x8*>(Qhi + qsrc);
  bf16x8 qh1 = *reinterpret_cast<const bf16x8*>(Qhi + qsrc + 32);
  bf16x8 ql0 = *reinterpret_cast<const bf16x8*>(Qlo + qsrc);
  bf16x8 ql1 = *reinterpret_cast<const bf16x8*>(Qlo + qsrc + 32);

  f32x2 aA01[12], aA23[12], aB01[12], aB23[12];
#pragma unroll
  for (int o = 0; o < 12; ++o) {
    aA01[o] = (f32x2){0.f, 0.f}; aA23[o] = (f32x2){0.f, 0.f};
    aB01[o] = (f32x2){0.f, 0.f}; aB23[o] = (f32x2){0.f, 0.f};
  }

  const int browA = lr, browB = 16 + lr;
  const int aiA0 = browA * 64 + ((lg + 0) ^ (browA & 7)) * 8;
  const int aiA1 = browA * 64 + ((lg + 4) ^ (browA & 7)) * 8;
  const int aiB0 = browB * 64 + ((lg + 0) ^ (browB & 7)) * 8;
  const int aiB1 = browB * 64 + ((lg + 4) ^ (browB & 7)) * 8;
  __syncthreads();

  int buf = 0;
#pragma unroll 2
  for (int h = 0; h < H_; ++h) {
    bf16x8 nqh0, nqh1, nql0, nql1;
    if (h < 11) {
      const size_t cs = csrc + (size_t)(h + 1) * hstep;
      GLLDS16(KChi + cs, &sCh[buf ^ 1][wv * 512]);
      GLLDS16(KClo + cs, &sCl[buf ^ 1][wv * 512]);
      const size_t qs = qsrc + (size_t)(h + 1) * hstep;
      nqh0 = *reinterpret_cast<const bf16x8*>(Qhi + qs);
      nqh1 = *reinterpret_cast<const bf16x8*>(Qhi + qs + 32);
      nql0 = *reinterpret_cast<const bf16x8*>(Qlo + qs);
      nql1 = *reinterpret_cast<const bf16x8*>(Qlo + qs + 32);
    }
    const bf16x8 chA0 = *reinterpret_cast<const bf16x8*>(&sCh[buf][aiA0]);
    const bf16x8 chA1 = *reinterpret_cast<const bf16x8*>(&sCh[buf][aiA1]);
    const bf16x8 clA0 = *reinterpret_cast<const bf16x8*>(&sCl[buf][aiA0]);
    const bf16x8 clA1 = *reinterpret_cast<const bf16x8*>(&sCl[buf][aiA1]);
    const bf16x8 chB0 = *reinterpret_cast<const bf16x8*>(&sCh[buf][aiB0]);
    const bf16x8 chB1 = *reinterpret_cast<const bf16x8*>(&sCh[buf][aiB1]);
    const bf16x8 clB0 = *reinterpret_cast<const bf16x8*>(&sCl[buf][aiB0]);
    const bf16x8 clB1 = *reinterpret_cast<const bf16x8*>(&sCl[buf][aiB1]);

    f32x4 uaA = {0.f, 0.f, 0.f, 0.f}, ubA = {0.f, 0.f, 0.f, 0.f};
    f32x4 uaB = {0.f, 0.f, 0.f, 0.f}, ubB = {0.f, 0.f, 0.f, 0.f};
    uaA = MFMA16(qh0, chA0, uaA);  ubA = MFMA16(qh1, chA1, ubA);
    uaB = MFMA16(qh0, chB0, uaB);  ubB = MFMA16(qh1, chB1, ubB);
    uaA = MFMA16(qh0, clA0, uaA);  ubA = MFMA16(qh1, clA1, ubA);
    uaB = MFMA16(qh0, clB0, uaB);  ubB = MFMA16(qh1, clB1, ubB);
    uaA = MFMA16(ql0, chA0, uaA);  ubA = MFMA16(ql1, chA1, ubA);
    uaB = MFMA16(ql0, chB0, uaB);  ubB = MFMA16(ql1, chB1, ubB);

    const float4 qm4 = *reinterpret_cast<const float4*>(&sQm[h][wv * 16 + lg * 4]);
    const float kmA = 64.0f * sKm[h][lr];
    const float kmB = 64.0f * sKm[h][16 + lr];
    const f32x2 qm01 = {qm4.x, qm4.y};
    const f32x2 qm23 = {qm4.z, qm4.w};
    const f32x2 uA01 = {uaA[0] + ubA[0], uaA[1] + ubA[1]};
    const f32x2 uA23 = {uaA[2] + ubA[2], uaA[3] + ubA[3]};
    const f32x2 uB01 = {uaB[0] + ubB[0], uaB[1] + ubB[1]};
    const f32x2 uB23 = {uaB[2] + ubB[2], uaB[3] + ubB[3]};
    const f32x2 svA01 = kmA * qm01 + uA01;
    const f32x2 svA23 = kmA * qm23 + uA23;
    const f32x2 svB01 = kmB * qm01 + uB01;
    const f32x2 svB23 = kmB * qm23 + uB23;
    const f32x2 u2A01 = uA01 * uA01;
    const f32x2 u2A23 = uA23 * uA23;
    const f32x2 u2B01 = uB01 * uB01;
    const f32x2 u2B23 = uB23 * uB23;
#pragma unroll
    for (int o = 0; o < 12; ++o) {
      const float we = Wfold[o * 24 + h];
      const float wr = Wfold[o * 24 + 12 + h];
      aA01[o] = aA01[o] + we * svA01 + wr * u2A01;
      aA23[o] = aA23[o] + we * svA23 + wr * u2A23;
      aB01[o] = aB01[o] + we * svB01 + wr * u2B01;
      aB23[o] = aB23[o] + we * svB23 + wr * u2B23;
    }
    __syncthreads();
    buf ^= 1;
    if (h < 11) { qh0 = nqh0; qh1 = nqh1; ql0 = nql0; ql1 = nql1; }
  }

#pragma unroll
  for (int o = 0; o < 12; ++o) {
    float* dst = &logits[((bh0 + o) * N_ + nb) * N_ + m0 + lr];
    dst[(size_t)(lg * 4 + 0) * N_] = aA01[o][0];
    dst[(size_t)(lg * 4 + 1) * N_] = aA01[o][1];
    dst[(size_t)(lg * 4 + 2) * N_] = aA23[o][0];
    dst[(size_t)(lg * 4 + 3) * N_] = aA23[o][1];
    dst[(size_t)(lg * 4 + 0) * N_ + 16] = aB01[o][0];
    dst[(size_t)(lg * 4 + 1) * N_ + 16] = aB01[o][1];
    dst[(size_t)(lg * 4 + 2) * N_ + 16] = aB23[o][0];
    dst[(size_t)(lg * 4 + 3) * N_ + 16] = aB23[o][1];
  }
#pragma unroll
  for (int o = 0; o < 12; ++o) {
    float avA[4] = {aA01[o][0], aA01[o][1], aA23[o][0], aA23[o][1]};
    float avB[4] = {aB01[o][0], aB01[o][1], aB23[o][0], aB23[o][1]};
    float M4[4], S4[4];
#pragma unroll
    for (int r = 0; r < 4; ++r) {
      float mxA = avA[r], mxB = avB[r];
      mxA = fmaxf(mxA, __shfl_xor(mxA, 1)); mxB = fmaxf(mxB, __shfl_xor(mxB, 1));
      mxA = fmaxf(mxA, __shfl_xor(mxA, 2)); mxB = fmaxf(mxB, __shfl_xor(mxB, 2));
      mxA = fmaxf(mxA, __shfl_xor(mxA, 4)); mxB = fmaxf(mxB, __shfl_xor(mxB, 4));
      mxA = fmaxf(mxA, __shfl_xor(mxA, 8)); mxB = fmaxf(mxB, __shfl_xor(mxB, 8));
      const float M = fmaxf(mxA, mxB);
      float eA = __expf(avA[r] - M);
      float eB = __expf(avB[r] - M);
      float e = eA + eB;
      e += __shfl_xor(e, 1);
      e += __shfl_xor(e, 2);
      e += __shfl_xor(e, 4);
      e += __shfl_xor(e, 8);
      M4[r] = M; S4[r] = e;
    }
    if (lr < 4) {
      const int n = nb + lg * 4 + lr;
      stats[(((size_t)b * 12 + o) * 32 + blockIdx.x) * 1024 + n] = make_float2(M4[lr], S4[lr]);
    }
  }
}

// ---------------- merge partial stats -> per-row (M, 1/S) ----------------
__global__ __launch_bounds__(256) void k_merge(const float2* __restrict__ stats,
                                               float2* __restrict__ merged) {
  const int bo = blockIdx.y;
  const int n = blockIdx.x * 256 + threadIdx.x;
  float M = -3.0e38f, S = 0.f;
  for (int seg = 0; seg < 32; ++seg) {
    const float2 p = stats[((size_t)bo * 32 + seg) * 1024 + n];
    if (p.x > M) {
      S = S * __expf(M - p.x) + p.y;
      M = p.x;
    } else {
      S += p.y * __expf(p.x - M);
    }
  }
  merged[(size_t)bo * 1024 + n] = make_float2(M, 1.0f / S);
}

// ---------------- fused softmax + attn-write + PV MFMA (64n x 64m chunks, bf16 V dbuf) ----------------
// R13 structure + XCD-aware block swizzle: 768 blocks, 96 logical per XCD so the
// 16 blocks sharing one (b,o) V panel co-reside on one XCD's L2.
__global__ __launch_bounds__(256) void k_pvsm(float* __restrict__ attn,
                                              const float2* __restrict__ merged,
                                              const short* __restrict__ Vt,
                                              short* __restrict__ ohi,
                                              short* __restrict__ olo) {
  __shared__ __align__(16) short sPhi[64 * 64];
  __shared__ __align__(16) short sPlo[64 * 64];
  __shared__ __align__(16) short sV[2][64 * 64];
  __shared__ float sM[64], sIS[64];
  // XCD swizzle: flat (x + y*16 + z*192) in [0,768); 768 % 8 == 0 -> bijective
  const int flat = blockIdx.x + blockIdx.y * 16 + blockIdx.z * 192;
  const int swz = (flat & 7) * 96 + (flat >> 3);
  const int b = swz / 192;
  const int rem = swz - b * 192;
  const int o = rem >> 4;
  const int n0 = (rem & 15) * 64;
  const int bo = b * H_ + o;
  const int t = threadIdx.x;
  const int wv = t >> 6, l = t & 63;
  const int lr = l & 15, lg = l >> 4;
  const int nsub = wv * 16;

  const int vr0 = t >> 3, vr1 = vr0 + 32;
  const int vc0 = (t & 7) ^ (vr0 & 7);
  const int vc1 = (t & 7) ^ (vr1 & 7);
  const size_t vbase = (size_t)bo * D_ * N_;
  const size_t vs0 = vbase + (size_t)vr0 * N_ + vc0 * 8;
  const size_t vs1 = vbase + (size_t)vr1 * N_ + vc1 * 8;

  if (t < 64) {
    const float2 ms = merged[(size_t)bo * 1024 + n0 + t];
    sM[t] = ms.x;
    sIS[t] = ms.y;
  }
  GLLDS16(Vt + vs0, &sV[0][(wv * 64) * 8]);
  GLLDS16(Vt + vs1, &sV[0][(wv * 64 + 256) * 8]);

  const int prow = t >> 3, c0 = (t & 7) * 8;
  float* lrowA = attn + ((size_t)bo * N_ + n0 + prow) * N_;
  float* lrowB = attn + ((size_t)bo * N_ + n0 + prow + 32) * N_;
  const int pofsA = prow * 64 + (((t & 7) ^ (prow & 7)) * 8);
  const int pofsB = pofsA + 32 * 64;

  const int arow = nsub + lr;
  const int ai0 = arow * 64 + (((lg + 0) ^ (arow & 7)) * 8);
  const int ai1 = arow * 64 + (((lg + 4) ^ (arow & 7)) * 8);

  f32x4 acc[4];
#pragma unroll
  for (int dt = 0; dt < 4; ++dt) acc[dt] = (f32x4){0.f, 0.f, 0.f, 0.f};
  __syncthreads();

  for (int mc = 0; mc < 16; ++mc) {
    const int m0 = mc * 64;
    if (mc < 15) {
      const int nb2 = (mc + 1) & 1;
      GLLDS16(Vt + vs0 + m0 + 64, &sV[nb2][(wv * 64) * 8]);
      GLLDS16(Vt + vs1 + m0 + 64, &sV[nb2][(wv * 64 + 256) * 8]);
    }
    const float MrA = sM[prow], iSA = sIS[prow];
    const float MrB = sM[prow + 32], iSB = sIS[prow + 32];
    float4 laA = *reinterpret_cast<const float4*>(&lrowA[m0 + c0]);
    float4 lbA = *reinterpret_cast<const float4*>(&lrowA[m0 + c0 + 4]);
    float4 laB = *reinterpret_cast<const float4*>(&lrowB[m0 + c0]);
    float4 lbB = *reinterpret_cast<const float4*>(&lrowB[m0 + c0 + 4]);
    float pA[8], pB[8];
    pA[0] = __expf(laA.x - MrA) * iSA; pA[1] = __expf(laA.y - MrA) * iSA;
    pA[2] = __expf(laA.z - MrA) * iSA; pA[3] = __expf(laA.w - MrA) * iSA;
    pA[4] = __expf(lbA.x - MrA) * iSA; pA[5] = __expf(lbA.y - MrA) * iSA;
    pA[6] = __expf(lbA.z - MrA) * iSA; pA[7] = __expf(lbA.w - MrA) * iSA;
    pB[0] = __expf(laB.x - MrB) * iSB; pB[1] = __expf(laB.y - MrB) * iSB;
    pB[2] = __expf(laB.z - MrB) * iSB; pB[3] = __expf(laB.w - MrB) * iSB;
    pB[4] = __expf(lbB.x - MrB) * iSB; pB[5] = __expf(lbB.y - MrB) * iSB;
    pB[6] = __expf(lbB.z - MrB) * iSB; pB[7] = __expf(lbB.w - MrB) * iSB;
    float4 oaA = {pA[0], pA[1], pA[2], pA[3]};
    float4 obA = {pA[4], pA[5], pA[6], pA[7]};
    float4 oaB = {pB[0], pB[1], pB[2], pB[3]};
    float4 obB = {pB[4], pB[5], pB[6], pB[7]};
    *reinterpret_cast<float4*>(&lrowA[m0 + c0]) = oaA;
    *reinterpret_cast<float4*>(&lrowA[m0 + c0 + 4]) = obA;
    *reinterpret_cast<float4*>(&lrowB[m0 + c0]) = oaB;
    *reinterpret_cast<float4*>(&lrowB[m0 + c0 + 4]) = obB;
    bf16x8 phiA, ploA, phiB, ploB;
#pragma unroll
    for (int j = 0; j < 8; ++j) {
      unsigned short hA = f2bf(pA[j]);
      phiA[j] = (short)hA;
      ploA[j] = (short)f2bf(pA[j] - bf2f(hA));
      unsigned short hB = f2bf(pB[j]);
      phiB[j] = (short)hB;
      ploB[j] = (short)f2bf(pB[j] - bf2f(hB));
    }
    *reinterpret_cast<bf16x8*>(&sPhi[pofsA]) = phiA;
    *reinterpret_cast<bf16x8*>(&sPlo[pofsA]) = ploA;
    *reinterpret_cast<bf16x8*>(&sPhi[pofsB]) = phiB;
    *reinterpret_cast<bf16x8*>(&sPlo[pofsB]) = ploB;
    __syncthreads();

    const int cur = mc & 1;
    const bf16x8 pah0 = *reinterpret_cast<const bf16x8*>(&sPhi[ai0]);
    const bf16x8 pah1 = *reinterpret_cast<const bf16x8*>(&sPhi[ai1]);
    const bf16x8 pal0 = *reinterpret_cast<const bf16x8*>(&sPlo[ai0]);
    const bf16x8 pal1 = *reinterpret_cast<const bf16x8*>(&sPlo[ai1]);
#pragma unroll
    for (int dt = 0; dt < 4; ++dt) {
      const int drow = dt * 16 + lr;
      const bf16x8 vh0 = *reinterpret_cast<const bf16x8*>(&sV[cur][drow * 64 + (((lg + 0) ^ (drow & 7)) * 8)]);
      const bf16x8 vh1 = *reinterpret_cast<const bf16x8*>(&sV[cur][drow * 64 + (((lg + 4) ^ (drow & 7)) * 8)]);
      acc[dt] = MFMA16(pah0, vh0, acc[dt]);
      acc[dt] = MFMA16(pal0, vh0, acc[dt]);
      acc[dt] = MFMA16(pah1, vh1, acc[dt]);
      acc[dt] = MFMA16(pal1, vh1, acc[dt]);
    }
    __syncthreads();
  }
#pragma unroll
  for (int dt = 0; dt < 4; ++dt) {
    const int d = dt * 16 + lr;
#pragma unroll
    for (int r = 0; r < 4; ++r) {
      const int n = n0 + nsub + lg * 4 + r;
      const float val = acc[dt][r];
      const unsigned short hh = f2bf(val);
      const size_t oo = (size_t)(b * 1024 + n) * 768 + o * 64 + d;
      ohi[oo] = (short)hh;
      olo[oo] = (short)f2bf(val - bf2f(hh));
    }
  }
}

extern "C" void kernel_launch(void* const* d_in, const int* in_sizes, int n_in,
                              void* d_out, int out_size, void* d_ws, size_t ws_size,
                              hipStream_t stream) {
  (void)in_sizes; (void)n_in; (void)out_size; (void)ws_size;
  const float* x      = (const float*)d_in[0];
  const float* W_qkv  = (const float*)d_in[1];
  const float* b_qkv  = (const float*)d_in[2];
  const float* scale  = (const float*)d_in[3];
  const float* riem   = (const float*)d_in[4];
  const float* W_conv = (const float*)d_in[5];
  // d_in[6] = b_conv: constant along softmax axis -> softmax-invariant, skipped
  const float* W_proj = (const float*)d_in[7];
  const float* b_proj = (const float*)d_in[8];

  float* out_final = (float*)d_out;                     // [B,N,C]
  float* attn_out  = out_final + (size_t)B_ * N_ * C_;  // [B,H,N,N] logits -> attn in-place

  char* w = (char*)d_ws;
  short* xhi  = (short*)w;                       // 6291456 B
  short* xlo  = xhi + 3145728;                   // 6291456 B
  short* Wthi = (short*)(w + 12582912);          // 3538944 B
  short* Wtlo = Wthi + 1769472;                  // 3538944 B
  short* Wpthi = (short*)(w + 19660800);         // 1179648 B
  short* Wptlo = Wpthi + 589824;                 // 1179648 B
  float* qkvf = (float*)(w + 22020096);          // 37748736 B
  short* Qhi  = (short*)(w + 59768832);
  short* Qlo  = Qhi + 3145728;
  short* KChi = Qlo + 3145728;
  short* KClo = KChi + 3145728;                  // ws end: 84934656 B
  // aliases (lifetime-disjoint)
  short* Vt = xhi;                               // after k_gemm128(qkv), x splits dead (single bf16)
  float* Wfold = (float*)Wthi;                   // Wt dead after qkv gemm (1152 B)
  float* Qm = (float*)((char*)Wthi + 8192);      // 196608 B
  float* Km = (float*)((char*)Wthi + 8192 + 196608);
  float2* stats  = (float2*)((char*)qkvf + 12582912);
  float2* merged = (float2*)((char*)qkvf + 25165824);
  short* ohi = Qhi;                              // after k_scores, Q splits dead
  short* olo = Qlo;

  k_split_x<<<dim3(1536), 256, 0, stream>>>(x, xhi, xlo);
  k_split_T<<<dim3(72, 24), 256, 0, stream>>>(W_qkv, Wthi, Wtlo, 768, 2304);
  k_split_T<<<dim3(24, 24), 256, 0, stream>>>(W_proj, Wpthi, Wptlo, 768, 768);
  k_gemm128<<<dim3(18, 32), 256, 0, stream>>>(xhi, xlo, Wthi, Wtlo, b_qkv, qkvf, 4096, 2304, 768);
  k_fold<<<dim3(1), 256, 0, stream>>>(W_conv, scale, riem, Wfold);
  k_qkv_post<<<dim3(32, 12, 4), 256, 0, stream>>>(qkvf, Qhi, Qlo, KChi, KClo, Vt, Qm, Km);
  k_scores<<<dim3(32, 16, 4), 256, 0, stream>>>(Qhi, Qlo, KChi, KClo, Qm, Km, Wfold, attn_out, stats);
  k_merge<<<dim3(4, 48), 256, 0, stream>>>(stats, merged);
  k_pvsm<<<dim3(16, 12, 4), 256, 0, stream>>>(attn_out, merged, Vt, ohi, olo);
  k_gemm<<<dim3(12, 32), 256, 0, stream>>>(ohi, olo, Wpthi, Wptlo, b_proj, out_final, 4096, 768, 768);
}

// Round 16
// 348.427 us; speedup vs baseline: 1.0717x; 1.0256x over previous
//
#include <hip/hip_runtime.h>
#include <cstddef>
#include <cstdint>

#define B_ 4
#define N_ 1024
#define C_ 768
#define H_ 12
#define D_ 64

typedef __attribute__((ext_vector_type(8))) short bf16x8;
typedef __attribute__((ext_vector_type(4))) short s16x4;
typedef __attribute__((ext_vector_type(4))) float f32x4;
typedef __attribute__((ext_vector_type(2))) float f32x2;

#define MFMA16(a_, b_, c_) __builtin_amdgcn_mfma_f32_16x16x32_bf16((a_), (b_), (c_), 0, 0, 0)
#define GLLDS16(gp_, lp_) __builtin_amdgcn_global_load_lds( \
    (const __attribute__((address_space(1))) unsigned int*)(gp_), \
    (__attribute__((address_space(3))) unsigned int*)(lp_), 16, 0, 0)

__device__ __forceinline__ unsigned short f2bf(float f) {
  unsigned int u = __float_as_uint(f);
  u += 0x7fffu + ((u >> 16) & 1u);
  return (unsigned short)(u >> 16);
}
__device__ __forceinline__ float bf2f(unsigned short b) {
  return __uint_as_float(((unsigned int)b) << 16);
}

// ---------------- fused prep: split x + split/transpose both weight matrices ----------------
// blocks [0,1536): split_x; [1536,3264): split_T(W_qkv); [3264,3840): split_T(W_proj)
__global__ __launch_bounds__(256) void k_prep(const float* __restrict__ x,
                                              short* __restrict__ xhi, short* __restrict__ xlo,
                                              const float* __restrict__ Wq,
                                              short* __restrict__ Wthi, short* __restrict__ Wtlo,
                                              const float* __restrict__ Wp,
                                              short* __restrict__ Wpthi, short* __restrict__ Wptlo) {
  __shared__ float tile[32][33];
  const int f = blockIdx.x;
  const int t = threadIdx.x;
  if (f < 1536) {
    const size_t i = ((size_t)f * 256 + t) * 8;
    float4 a = *reinterpret_cast<const float4*>(&x[i]);
    float4 b = *reinterpret_cast<const float4*>(&x[i + 4]);
    float v[8] = {a.x, a.y, a.z, a.w, b.x, b.y, b.z, b.w};
    bf16x8 hi, lo;
#pragma unroll
    for (int j = 0; j < 8; ++j) {
      unsigned short h = f2bf(v[j]);
      hi[j] = (short)h;
      lo[j] = (short)f2bf(v[j] - bf2f(h));
    }
    *reinterpret_cast<bf16x8*>(&xhi[i]) = hi;
    *reinterpret_cast<bf16x8*>(&xlo[i]) = lo;
    return;
  }
  const float* W;
  short *Thi, *Tlo;
  int Kd, Nn, bx, by;
  if (f < 3264) {
    const int local = f - 1536;
    W = Wq; Thi = Wthi; Tlo = Wtlo; Kd = 768; Nn = 2304;
    bx = local % 72; by = local / 72;
  } else {
    const int local = f - 3264;
    W = Wp; Thi = Wpthi; Tlo = Wptlo; Kd = 768; Nn = 768;
    bx = local % 24; by = local / 24;
  }
  const int k0 = by * 32, n0 = bx * 32;
  const int r = t >> 3, cq = (t & 7) * 4;
  float4 v = *reinterpret_cast<const float4*>(&W[(size_t)(k0 + r) * Nn + n0 + cq]);
  tile[r][cq + 0] = v.x; tile[r][cq + 1] = v.y;
  tile[r][cq + 2] = v.z; tile[r][cq + 3] = v.w;
  __syncthreads();
  const int nrow = t >> 3, kq = (t & 7) * 4;
  s16x4 hi, lo;
#pragma unroll
  for (int i = 0; i < 4; ++i) {
    float fv = tile[kq + i][nrow];
    unsigned short h = f2bf(fv);
    hi[i] = (short)h;
    lo[i] = (short)f2bf(fv - bf2f(h));
  }
  *reinterpret_cast<s16x4*>(&Thi[(size_t)(n0 + nrow) * Kd + k0 + kq]) = hi;
  *reinterpret_cast<s16x4*>(&Tlo[(size_t)(n0 + nrow) * Kd + k0 + kq]) = lo;
}

// ---------------- fold scale/riem into W_conv ----------------
__global__ __launch_bounds__(256) void k_fold(const float* __restrict__ Wc,
                                              const float* __restrict__ scale_p,
                                              const float* __restrict__ riem_p,
                                              float* __restrict__ Wfold) {
  const int t = threadIdx.x;
  const float scale = scale_p[0], riem = riem_p[0];
  for (int i = t; i < 288; i += 256)
    Wfold[i] = Wc[i] * (((i % 24) < 12) ? scale : riem);
}

// ---------------- split-bf16 MFMA GEMM, BM=128 BN=64 BK=32 (for proj) ----------------
__global__ __launch_bounds__(256) void k_gemm(const short* __restrict__ Ahi,
                                              const short* __restrict__ Alo,
                                              const short* __restrict__ Bhi,
                                              const short* __restrict__ Blo,
                                              const float* __restrict__ bias,
                                              float* __restrict__ Cout,
                                              int M, int Nn, int Kd) {
  __shared__ __align__(16) short sA[2][128 * 32];
  __shared__ __align__(16) short sB[2][64 * 32];
  const int tid = threadIdx.x;
  const int wv = tid >> 6, l = tid & 63;
  const int lr = l & 15, lg = l >> 4;
  const int row0 = blockIdx.y * 128;
  const int col0 = blockIdx.x * 64;
  const int wr = (wv >> 1) * 64;
  const int wc = (wv & 1) * 32;
  const int ar = tid >> 2, ac = tid & 3;
  f32x4 acc[4][2];
#pragma unroll
  for (int i = 0; i < 4; ++i)
#pragma unroll
    for (int j = 0; j < 2; ++j) acc[i][j] = (f32x4){0.f, 0.f, 0.f, 0.f};

  for (int k0 = 0; k0 < Kd; k0 += 32) {
#pragma unroll
    for (int j = 0; j < 2; ++j) {
      const int row = j * 64 + ar;
      const int cc = ac ^ ((row >> 1) & 3);
      const size_t so = (size_t)(row0 + row) * Kd + k0 + cc * 8;
      GLLDS16(Ahi + so, &sA[0][(j * 256 + (wv << 6)) * 8]);
      GLLDS16(Alo + so, &sA[1][(j * 256 + (wv << 6)) * 8]);
    }
    {
      const int row = ar;
      const int cc = ac ^ ((row >> 1) & 3);
      const size_t so = (size_t)(col0 + row) * Kd + k0 + cc * 8;
      GLLDS16(Bhi + so, &sB[0][(wv << 6) * 8]);
      GLLDS16(Blo + so, &sB[1][(wv << 6) * 8]);
    }
    __syncthreads();
    bf16x8 afh[4], afl[4], bfh[2], bfl[2];
#pragma unroll
    for (int ti = 0; ti < 4; ++ti) {
      const int row = wr + ti * 16 + lr;
      const int pc = lg ^ ((row >> 1) & 3);
      afh[ti] = *reinterpret_cast<const bf16x8*>(&sA[0][row * 32 + pc * 8]);
      afl[ti] = *reinterpret_cast<const bf16x8*>(&sA[1][row * 32 + pc * 8]);
    }
#pragma unroll
    for (int tj = 0; tj < 2; ++tj) {
      const int row = wc + tj * 16 + lr;
      const int pc = lg ^ ((row >> 1) & 3);
      bfh[tj] = *reinterpret_cast<const bf16x8*>(&sB[0][row * 32 + pc * 8]);
      bfl[tj] = *reinterpret_cast<const bf16x8*>(&sB[1][row * 32 + pc * 8]);
    }
#pragma unroll
    for (int ti = 0; ti < 4; ++ti)
#pragma unroll
      for (int tj = 0; tj < 2; ++tj) {
        acc[ti][tj] = MFMA16(afh[ti], bfh[tj], acc[ti][tj]);
        acc[ti][tj] = MFMA16(afl[ti], bfh[tj], acc[ti][tj]);
        acc[ti][tj] = MFMA16(afh[ti], bfl[tj], acc[ti][tj]);
      }
    __syncthreads();
  }
#pragma unroll
  for (int ti = 0; ti < 4; ++ti)
#pragma unroll
    for (int tj = 0; tj < 2; ++tj) {
      const int col = col0 + wc + tj * 16 + lr;
      const float bb = bias[col];
#pragma unroll
      for (int r = 0; r < 4; ++r) {
        const int row = row0 + wr + ti * 16 + lg * 4 + r;
        Cout[(size_t)row * Nn + col] = acc[ti][tj][r] + bb;
      }
    }
}

// ---------------- split-bf16 MFMA GEMM, BM=128 BN=128 BK=32 (for qkv) ----------------
__global__ __launch_bounds__(256) void k_gemm128(const short* __restrict__ Ahi,
                                                 const short* __restrict__ Alo,
                                                 const short* __restrict__ Bhi,
                                                 const short* __restrict__ Blo,
                                                 const float* __restrict__ bias,
                                                 float* __restrict__ Cout,
                                                 int M, int Nn, int Kd) {
  __shared__ __align__(16) short sA[2][128 * 32];
  __shared__ __align__(16) short sB[2][128 * 32];
  const int tid = threadIdx.x;
  const int wv = tid >> 6, l = tid & 63;
  const int lr = l & 15, lg = l >> 4;
  const int row0 = blockIdx.y * 128;
  const int col0 = blockIdx.x * 128;
  const int wr = (wv >> 1) * 64;
  const int wc = (wv & 1) * 64;
  const int ar = tid >> 2, ac = tid & 3;
  f32x4 acc[4][4];
#pragma unroll
  for (int i = 0; i < 4; ++i)
#pragma unroll
    for (int j = 0; j < 4; ++j) acc[i][j] = (f32x4){0.f, 0.f, 0.f, 0.f};

  for (int k0 = 0; k0 < Kd; k0 += 32) {
#pragma unroll
    for (int j = 0; j < 2; ++j) {
      const int row = j * 64 + ar;
      const int cc = ac ^ ((row >> 1) & 3);
      const size_t ao = (size_t)(row0 + row) * Kd + k0 + cc * 8;
      const size_t bo = (size_t)(col0 + row) * Kd + k0 + cc * 8;
      GLLDS16(Ahi + ao, &sA[0][(j * 256 + (wv << 6)) * 8]);
      GLLDS16(Alo + ao, &sA[1][(j * 256 + (wv << 6)) * 8]);
      GLLDS16(Bhi + bo, &sB[0][(j * 256 + (wv << 6)) * 8]);
      GLLDS16(Blo + bo, &sB[1][(j * 256 + (wv << 6)) * 8]);
    }
    __syncthreads();
    bf16x8 afh[4], afl[4], bfh[4], bfl[4];
#pragma unroll
    for (int ti = 0; ti < 4; ++ti) {
      const int row = wr + ti * 16 + lr;
      const int pc = lg ^ ((row >> 1) & 3);
      afh[ti] = *reinterpret_cast<const bf16x8*>(&sA[0][row * 32 + pc * 8]);
      afl[ti] = *reinterpret_cast<const bf16x8*>(&sA[1][row * 32 + pc * 8]);
    }
#pragma unroll
    for (int tj = 0; tj < 4; ++tj) {
      const int row = wc + tj * 16 + lr;
      const int pc = lg ^ ((row >> 1) & 3);
      bfh[tj] = *reinterpret_cast<const bf16x8*>(&sB[0][row * 32 + pc * 8]);
      bfl[tj] = *reinterpret_cast<const bf16x8*>(&sB[1][row * 32 + pc * 8]);
    }
#pragma unroll
    for (int ti = 0; ti < 4; ++ti)
#pragma unroll
      for (int tj = 0; tj < 4; ++tj) {
        acc[ti][tj] = MFMA16(afh[ti], bfh[tj], acc[ti][tj]);
        acc[ti][tj] = MFMA16(afl[ti], bfh[tj], acc[ti][tj]);
        acc[ti][tj] = MFMA16(afh[ti], bfl[tj], acc[ti][tj]);
      }
    __syncthreads();
  }
#pragma unroll
  for (int ti = 0; ti < 4; ++ti)
#pragma unroll
    for (int tj = 0; tj < 4; ++tj) {
      const int col = col0 + wc + tj * 16 + lr;
      const float bb = bias[col];
#pragma unroll
      for (int r = 0; r < 4; ++r) {
        const int row = row0 + wr + ti * 16 + lg * 4 + r;
        Cout[(size_t)row * Nn + col] = acc[ti][tj][r] + bb;
      }
    }
}

// ---------------- qkv post: split Q, center+split K, means, transpose V (single bf16) ----------------
__global__ __launch_bounds__(256) void k_qkv_post(const float* __restrict__ qkvf,
                                                  short* __restrict__ Qhi, short* __restrict__ Qlo,
                                                  short* __restrict__ KChi, short* __restrict__ KClo,
                                                  short* __restrict__ Vt,
                                                  float* __restrict__ Qm, float* __restrict__ Km) {
  __shared__ unsigned short lvh[64][33];
  const int b = blockIdx.z, h = blockIdx.y, n0 = blockIdx.x * 32;
  const int t = threadIdx.x;
  const int row = t >> 3, d0 = (t & 7) * 8;
  const int n = n0 + row;
  const float* base = qkvf + ((size_t)(b * 1024 + n)) * 2304 + h * 64 + d0;
  const size_t qko = ((size_t)(b * H_ + h) * N_ + n) * D_ + d0;

#pragma unroll
  for (int part = 0; part < 2; ++part) {  // 0: q, 1: k (centered)
    float4 a = *reinterpret_cast<const float4*>(base + part * 768);
    float4 c = *reinterpret_cast<const float4*>(base + part * 768 + 4);
    float v[8] = {a.x, a.y, a.z, a.w, c.x, c.y, c.z, c.w};
    float s = v[0] + v[1] + v[2] + v[3] + v[4] + v[5] + v[6] + v[7];
#pragma unroll
    for (int off = 1; off < 8; off <<= 1) s += __shfl_xor(s, off);
    const float mean = s * (1.0f / 64.0f);
    if ((t & 7) == 0) (part ? Km : Qm)[(size_t)(b * H_ + h) * N_ + n] = mean;
    const float sub = part ? mean : 0.0f;
    bf16x8 hi, lo;
#pragma unroll
    for (int j = 0; j < 8; ++j) {
      const float fv = v[j] - sub;
      unsigned short hh = f2bf(fv);
      hi[j] = (short)hh;
      lo[j] = (short)f2bf(fv - bf2f(hh));
    }
    *reinterpret_cast<bf16x8*>((part ? KChi : Qhi) + qko) = hi;
    *reinterpret_cast<bf16x8*>((part ? KClo : Qlo) + qko) = lo;
  }
  {  // v -> transposed single bf16
    float4 a = *reinterpret_cast<const float4*>(base + 1536);
    float4 c = *reinterpret_cast<const float4*>(base + 1536 + 4);
    float v[8] = {a.x, a.y, a.z, a.w, c.x, c.y, c.z, c.w};
#pragma unroll
    for (int j = 0; j < 8; ++j) lvh[d0 + j][row] = f2bf(v[j]);
  }
  __syncthreads();
  const int d = t >> 2, c = t & 3;
  bf16x8 vh;
#pragma unroll
  for (int i = 0; i < 8; ++i) vh[i] = (short)lvh[d][c * 8 + i];
  const size_t vo = ((size_t)(b * H_ + h) * D_ + d) * N_ + n0 + c * 8;
  *reinterpret_cast<bf16x8*>(Vt + vo) = vh;
}

// ---------------- scores + channel mix -> logits (+ per-block softmax stats) ----------------
// 64n x 32m block (best measured 148us). Each wave owns 16n x 32m.
__global__ __launch_bounds__(256, 2) void k_scores(
    const short* __restrict__ Qhi, const short* __restrict__ Qlo,
    const short* __restrict__ KChi, const short* __restrict__ KClo,
    const float* __restrict__ Qm, const float* __restrict__ Km,
    const float* __restrict__ Wfold, float* __restrict__ logits,
    float2* __restrict__ stats) {
  __shared__ __align__(16) short sCh[2][32 * 64];
  __shared__ __align__(16) short sCl[2][32 * 64];
  __shared__ float sQm[12][64];
  __shared__ float sKm[12][32];

  const int t = threadIdx.x;
  const int b = blockIdx.z;
  const int n0 = blockIdx.y * 64, m0 = blockIdx.x * 32;
  const int wv = t >> 6, l = t & 63;
  const int lr = l & 15, lg = l >> 4;
  const size_t bh0 = (size_t)b * H_;

  for (int i = t; i < 768; i += 256)
    sQm[i >> 6][i & 63] = Qm[(bh0 + (i >> 6)) * N_ + n0 + (i & 63)];
  for (int i = t; i < 384; i += 256)
    sKm[i >> 5][i & 31] = Km[(bh0 + (i >> 5)) * N_ + m0 + (i & 31)];

  const int srow = t >> 3;
  const int scs = (t & 7) ^ (srow & 7);
  const size_t csrc = (bh0 * N_ + m0 + srow) * D_ + scs * 8;
  const size_t hstep = (size_t)N_ * D_;
  const int nb = n0 + wv * 16;
  const size_t qsrc = (bh0 * N_ + nb + lr) * D_ + lg * 8;

  GLLDS16(KChi + csrc, &sCh[0][wv * 512]);
  GLLDS16(KClo + csrc, &sCl[0][wv * 512]);
  bf16x8 qh0 = *reinterpret_cast<const bf16x8*>(Qhi + qsrc);
  bf16x8 qh1 = *reinterpret_cast<const bf16x8*>(Qhi + qsrc + 32);
  bf16x8 ql0 = *reinterpret_cast<const bf16x8*>(Qlo + qsrc);
  bf16x8 ql1 = *reinterpret_cast<const bf16x8*>(Qlo + qsrc + 32);

  f32x2 aA01[12], aA23[12], aB01[12], aB23[12];
#pragma unroll
  for (int o = 0; o < 12; ++o) {
    aA01[o] = (f32x2){0.f, 0.f}; aA23[o] = (f32x2){0.f, 0.f};
    aB01[o] = (f32x2){0.f, 0.f}; aB23[o] = (f32x2){0.f, 0.f};
  }

  const int browA = lr, browB = 16 + lr;
  const int aiA0 = browA * 64 + ((lg + 0) ^ (browA & 7)) * 8;
  const int aiA1 = browA * 64 + ((lg + 4) ^ (browA & 7)) * 8;
  const int aiB0 = browB * 64 + ((lg + 0) ^ (browB & 7)) * 8;
  const int aiB1 = browB * 64 + ((lg + 4) ^ (browB & 7)) * 8;
  __syncthreads();

  int buf = 0;
#pragma unroll 2
  for (int h = 0; h < H_; ++h) {
    bf16x8 nqh0, nqh1, nql0, nql1;
    if (h < 11) {
      const size_t cs = csrc + (size_t)(h + 1) * hstep;
      GLLDS16(KChi + cs, &sCh[buf ^ 1][wv * 512]);
      GLLDS16(KClo + cs, &sCl[buf ^ 1][wv * 512]);
      const size_t qs = qsrc + (size_t)(h + 1) * hstep;
      nqh0 = *reinterpret_cast<const bf16x8*>(Qhi + qs);
      nqh1 = *reinterpret_cast<const bf16x8*>(Qhi + qs + 32);
      nql0 = *reinterpret_cast<const bf16x8*>(Qlo + qs);
      nql1 = *reinterpret_cast<const bf16x8*>(Qlo + qs + 32);
    }
    const bf16x8 chA0 = *reinterpret_cast<const bf16x8*>(&sCh[buf][aiA0]);
    const bf16x8 chA1 = *reinterpret_cast<const bf16x8*>(&sCh[buf][aiA1]);
    const bf16x8 clA0 = *reinterpret_cast<const bf16x8*>(&sCl[buf][aiA0]);
    const bf16x8 clA1 = *reinterpret_cast<const bf16x8*>(&sCl[buf][aiA1]);
    const bf16x8 chB0 = *reinterpret_cast<const bf16x8*>(&sCh[buf][aiB0]);
    const bf16x8 chB1 = *reinterpret_cast<const bf16x8*>(&sCh[buf][aiB1]);
    const bf16x8 clB0 = *reinterpret_cast<const bf16x8*>(&sCl[buf][aiB0]);
    const bf16x8 clB1 = *reinterpret_cast<const bf16x8*>(&sCl[buf][aiB1]);

    f32x4 uaA = {0.f, 0.f, 0.f, 0.f}, ubA = {0.f, 0.f, 0.f, 0.f};
    f32x4 uaB = {0.f, 0.f, 0.f, 0.f}, ubB = {0.f, 0.f, 0.f, 0.f};
    uaA = MFMA16(qh0, chA0, uaA);  ubA = MFMA16(qh1, chA1, ubA);
    uaB = MFMA16(qh0, chB0, uaB);  ubB = MFMA16(qh1, chB1, ubB);
    uaA = MFMA16(qh0, clA0, uaA);  ubA = MFMA16(qh1, clA1, ubA);
    uaB = MFMA16(qh0, clB0, uaB);  ubB = MFMA16(qh1, clB1, ubB);
    uaA = MFMA16(ql0, chA0, uaA);  ubA = MFMA16(ql1, chA1, ubA);
    uaB = MFMA16(ql0, chB0, uaB);  ubB = MFMA16(ql1, chB1, ubB);

    const float4 qm4 = *reinterpret_cast<const float4*>(&sQm[h][wv * 16 + lg * 4]);
    const float kmA = 64.0f * sKm[h][lr];
    const float kmB = 64.0f * sKm[h][16 + lr];
    const f32x2 qm01 = {qm4.x, qm4.y};
    const f32x2 qm23 = {qm4.z, qm4.w};
    const f32x2 uA01 = {uaA[0] + ubA[0], uaA[1] + ubA[1]};
    const f32x2 uA23 = {uaA[2] + ubA[2], uaA[3] + ubA[3]};
    const f32x2 uB01 = {uaB[0] + ubB[0], uaB[1] + ubB[1]};
    const f32x2 uB23 = {uaB[2] + ubB[2], uaB[3] + ubB[3]};
    const f32x2 svA01 = kmA * qm01 + uA01;
    const f32x2 svA23 = kmA * qm23 + uA23;
    const f32x2 svB01 = kmB * qm01 + uB01;
    const f32x2 svB23 = kmB * qm23 + uB23;
    const f32x2 u2A01 = uA01 * uA01;
    const f32x2 u2A23 = uA23 * uA23;
    const f32x2 u2B01 = uB01 * uB01;
    const f32x2 u2B23 = uB23 * uB23;
#pragma unroll
    for (int o = 0; o < 12; ++o) {
      const float we = Wfold[o * 24 + h];
      const float wr = Wfold[o * 24 + 12 + h];
      aA01[o] = aA01[o] + we * svA01 + wr * u2A01;
      aA23[o] = aA23[o] + we * svA23 + wr * u2A23;
      aB01[o] = aB01[o] + we * svB01 + wr * u2B01;
      aB23[o] = aB23[o] + we * svB23 + wr * u2B23;
    }
    __syncthreads();
    buf ^= 1;
    if (h < 11) { qh0 = nqh0; qh1 = nqh1; ql0 = nql0; ql1 = nql1; }
  }

#pragma unroll
  for (int o = 0; o < 12; ++o) {
    float* dst = &logits[((bh0 + o) * N_ + nb) * N_ + m0 + lr];
    dst[(size_t)(lg * 4 + 0) * N_] = aA01[o][0];
    dst[(size_t)(lg * 4 + 1) * N_] = aA01[o][1];
    dst[(size_t)(lg * 4 + 2) * N_] = aA23[o][0];
    dst[(size_t)(lg * 4 + 3) * N_] = aA23[o][1];
    dst[(size_t)(lg * 4 + 0) * N_ + 16] = aB01[o][0];
    dst[(size_t)(lg * 4 + 1) * N_ + 16] = aB01[o][1];
    dst[(size_t)(lg * 4 + 2) * N_ + 16] = aB23[o][0];
    dst[(size_t)(lg * 4 + 3) * N_ + 16] = aB23[o][1];
  }
#pragma unroll
  for (int o = 0; o < 12; ++o) {
    float avA[4] = {aA01[o][0], aA01[o][1], aA23[o][0], aA23[o][1]};
    float avB[4] = {aB01[o][0], aB01[o][1], aB23[o][0], aB23[o][1]};
    float M4[4], S4[4];
#pragma unroll
    for (int r = 0; r < 4; ++r) {
      float mxA = avA[r], mxB = avB[r];
      mxA = fmaxf(mxA, __shfl_xor(mxA, 1)); mxB = fmaxf(mxB, __shfl_xor(mxB, 1));
      mxA = fmaxf(mxA, __shfl_xor(mxA, 2)); mxB = fmaxf(mxB, __shfl_xor(mxB, 2));
      mxA = fmaxf(mxA, __shfl_xor(mxA, 4)); mxB = fmaxf(mxB, __shfl_xor(mxB, 4));
      mxA = fmaxf(mxA, __shfl_xor(mxA, 8)); mxB = fmaxf(mxB, __shfl_xor(mxB, 8));
      const float M = fmaxf(mxA, mxB);
      float eA = __expf(avA[r] - M);
      float eB = __expf(avB[r] - M);
      float e = eA + eB;
      e += __shfl_xor(e, 1);
      e += __shfl_xor(e, 2);
      e += __shfl_xor(e, 4);
      e += __shfl_xor(e, 8);
      M4[r] = M; S4[r] = e;
    }
    if (lr < 4) {
      const int n = nb + lg * 4 + lr;
      stats[(((size_t)b * 12 + o) * 32 + blockIdx.x) * 1024 + n] = make_float2(M4[lr], S4[lr]);
    }
  }
}

// ---------------- fused stats-merge + softmax + attn-write + PV MFMA (64n x 64m, bf16 V dbuf) ----------------
// Prologue merges the 32 partial stats for this block's 64 rows (replaces k_merge;
// each (bo,n) range is owned by exactly one block -> same total work, one less launch).
// XCD-aware swizzle: 96 logical blocks per XCD so V-panel-sharing blocks co-reside.
__global__ __launch_bounds__(256) void k_pvsm(float* __restrict__ attn,
                                              const float2* __restrict__ stats,
                                              const short* __restrict__ Vt,
                                              short* __restrict__ ohi,
                                              short* __restrict__ olo) {
  __shared__ __align__(16) short sPhi[64 * 64];
  __shared__ __align__(16) short sPlo[64 * 64];
  __shared__ __align__(16) short sV[2][64 * 64];
  __shared__ float sM[64], sIS[64];
  // XCD swizzle: flat (x + y*16 + z*192) in [0,768); 768 % 8 == 0 -> bijective
  const int flat = blockIdx.x + blockIdx.y * 16 + blockIdx.z * 192;
  const int swz = (flat & 7) * 96 + (flat >> 3);
  const int b = swz / 192;
  const int rem = swz - b * 192;
  const int o = rem >> 4;
  const int n0 = (rem & 15) * 64;
  const int bo = b * H_ + o;
  const int t = threadIdx.x;
  const int wv = t >> 6, l = t & 63;
  const int lr = l & 15, lg = l >> 4;
  const int nsub = wv * 16;

  const int vr0 = t >> 3, vr1 = vr0 + 32;
  const int vc0 = (t & 7) ^ (vr0 & 7);
  const int vc1 = (t & 7) ^ (vr1 & 7);
  const size_t vbase = (size_t)bo * D_ * N_;
  const size_t vs0 = vbase + (size_t)vr0 * N_ + vc0 * 8;
  const size_t vs1 = vbase + (size_t)vr1 * N_ + vc1 * 8;

  GLLDS16(Vt + vs0, &sV[0][(wv * 64) * 8]);
  GLLDS16(Vt + vs1, &sV[0][(wv * 64 + 256) * 8]);

  // merge partial stats for this block's 64 rows (was k_merge)
  if (t < 64) {
    const int n = n0 + t;
    const float2* sp = stats + ((size_t)bo * 32) * 1024 + n;
    float M = -3.0e38f, S = 0.f;
    for (int seg = 0; seg < 32; ++seg) {
      const float2 p = sp[(size_t)seg * 1024];
      if (p.x > M) {
        S = S * __expf(M - p.x) + p.y;
        M = p.x;
      } else {
        S += p.y * __expf(p.x - M);
      }
    }
    sM[t] = M;
    sIS[t] = 1.0f / S;
  }

  const int prow = t >> 3, c0 = (t & 7) * 8;
  float* lrowA = attn + ((size_t)bo * N_ + n0 + prow) * N_;
  float* lrowB = attn + ((size_t)bo * N_ + n0 + prow + 32) * N_;
  const int pofsA = prow * 64 + (((t & 7) ^ (prow & 7)) * 8);
  const int pofsB = pofsA + 32 * 64;

  const int arow = nsub + lr;
  const int ai0 = arow * 64 + (((lg + 0) ^ (arow & 7)) * 8);
  const int ai1 = arow * 64 + (((lg + 4) ^ (arow & 7)) * 8);

  f32x4 acc[4];
#pragma unroll
  for (int dt = 0; dt < 4; ++dt) acc[dt] = (f32x4){0.f, 0.f, 0.f, 0.f};
  __syncthreads();

  for (int mc = 0; mc < 16; ++mc) {
    const int m0 = mc * 64;
    if (mc < 15) {
      const int nb2 = (mc + 1) & 1;
      GLLDS16(Vt + vs0 + m0 + 64, &sV[nb2][(wv * 64) * 8]);
      GLLDS16(Vt + vs1 + m0 + 64, &sV[nb2][(wv * 64 + 256) * 8]);
    }
    const float MrA = sM[prow], iSA = sIS[prow];
    const float MrB = sM[prow + 32], iSB = sIS[prow + 32];
    float4 laA = *reinterpret_cast<const float4*>(&lrowA[m0 + c0]);
    float4 lbA = *reinterpret_cast<const float4*>(&lrowA[m0 + c0 + 4]);
    float4 laB = *reinterpret_cast<const float4*>(&lrowB[m0 + c0]);
    float4 lbB = *reinterpret_cast<const float4*>(&lrowB[m0 + c0 + 4]);
    float pA[8], pB[8];
    pA[0] = __expf(laA.x - MrA) * iSA; pA[1] = __expf(laA.y - MrA) * iSA;
    pA[2] = __expf(laA.z - MrA) * iSA; pA[3] = __expf(laA.w - MrA) * iSA;
    pA[4] = __expf(lbA.x - MrA) * iSA; pA[5] = __expf(lbA.y - MrA) * iSA;
    pA[6] = __expf(lbA.z - MrA) * iSA; pA[7] = __expf(lbA.w - MrA) * iSA;
    pB[0] = __expf(laB.x - MrB) * iSB; pB[1] = __expf(laB.y - MrB) * iSB;
    pB[2] = __expf(laB.z - MrB) * iSB; pB[3] = __expf(laB.w - MrB) * iSB;
    pB[4] = __expf(lbB.x - MrB) * iSB; pB[5] = __expf(lbB.y - MrB) * iSB;
    pB[6] = __expf(lbB.z - MrB) * iSB; pB[7] = __expf(lbB.w - MrB) * iSB;
    float4 oaA = {pA[0], pA[1], pA[2], pA[3]};
    float4 obA = {pA[4], pA[5], pA[6], pA[7]};
    float4 oaB = {pB[0], pB[1], pB[2], pB[3]};
    float4 obB = {pB[4], pB[5], pB[6], pB[7]};
    *reinterpret_cast<float4*>(&lrowA[m0 + c0]) = oaA;
    *reinterpret_cast<float4*>(&lrowA[m0 + c0 + 4]) = obA;
    *reinterpret_cast<float4*>(&lrowB[m0 + c0]) = oaB;
    *reinterpret_cast<float4*>(&lrowB[m0 + c0 + 4]) = obB;
    bf16x8 phiA, ploA, phiB, ploB;
#pragma unroll
    for (int j = 0; j < 8; ++j) {
      unsigned short hA = f2bf(pA[j]);
      phiA[j] = (short)hA;
      ploA[j] = (short)f2bf(pA[j] - bf2f(hA));
      unsigned short hB = f2bf(pB[j]);
      phiB[j] = (short)hB;
      ploB[j] = (short)f2bf(pB[j] - bf2f(hB));
    }
    *reinterpret_cast<bf16x8*>(&sPhi[pofsA]) = phiA;
    *reinterpret_cast<bf16x8*>(&sPlo[pofsA]) = ploA;
    *reinterpret_cast<bf16x8*>(&sPhi[pofsB]) = phiB;
    *reinterpret_cast<bf16x8*>(&sPlo[pofsB]) = ploB;
    __syncthreads();

    const int cur = mc & 1;
    const bf16x8 pah0 = *reinterpret_cast<const bf16x8*>(&sPhi[ai0]);
    const bf16x8 pah1 = *reinterpret_cast<const bf16x8*>(&sPhi[ai1]);
    const bf16x8 pal0 = *reinterpret_cast<const bf16x8*>(&sPlo[ai0]);
    const bf16x8 pal1 = *reinterpret_cast<const bf16x8*>(&sPlo[ai1]);
#pragma unroll
    for (int dt = 0; dt < 4; ++dt) {
      const int drow = dt * 16 + lr;
      const bf16x8 vh0 = *reinterpret_cast<const bf16x8*>(&sV[cur][drow * 64 + (((lg + 0) ^ (drow & 7)) * 8)]);
      const bf16x8 vh1 = *reinterpret_cast<const bf16x8*>(&sV[cur][drow * 64 + (((lg + 4) ^ (drow & 7)) * 8)]);
      acc[dt] = MFMA16(pah0, vh0, acc[dt]);
      acc[dt] = MFMA16(pal0, vh0, acc[dt]);
      acc[dt] = MFMA16(pah1, vh1, acc[dt]);
      acc[dt] = MFMA16(pal1, vh1, acc[dt]);
    }
    __syncthreads();
  }
#pragma unroll
  for (int dt = 0; dt < 4; ++dt) {
    const int d = dt * 16 + lr;
#pragma unroll
    for (int r = 0; r < 4; ++r) {
      const int n = n0 + nsub + lg * 4 + r;
      const float val = acc[dt][r];
      const unsigned short hh = f2bf(val);
      const size_t oo = (size_t)(b * 1024 + n) * 768 + o * 64 + d;
      ohi[oo] = (short)hh;
      olo[oo] = (short)f2bf(val - bf2f(hh));
    }
  }
}

extern "C" void kernel_launch(void* const* d_in, const int* in_sizes, int n_in,
                              void* d_out, int out_size, void* d_ws, size_t ws_size,
                              hipStream_t stream) {
  (void)in_sizes; (void)n_in; (void)out_size; (void)ws_size;
  const float* x      = (const float*)d_in[0];
  const float* W_qkv  = (const float*)d_in[1];
  const float* b_qkv  = (const float*)d_in[2];
  const float* scale  = (const float*)d_in[3];
  const float* riem   = (const float*)d_in[4];
  const float* W_conv = (const float*)d_in[5];
  // d_in[6] = b_conv: constant along softmax axis -> softmax-invariant, skipped
  const float* W_proj = (const float*)d_in[7];
  const float* b_proj = (const float*)d_in[8];

  float* out_final = (float*)d_out;                     // [B,N,C]
  float* attn_out  = out_final + (size_t)B_ * N_ * C_;  // [B,H,N,N] logits -> attn in-place

  char* w = (char*)d_ws;
  short* xhi  = (short*)w;                       // 6291456 B
  short* xlo  = xhi + 3145728;                   // 6291456 B
  short* Wthi = (short*)(w + 12582912);          // 3538944 B
  short* Wtlo = Wthi + 1769472;                  // 3538944 B
  short* Wpthi = (short*)(w + 19660800);         // 1179648 B
  short* Wptlo = Wpthi + 589824;                 // 1179648 B
  float* qkvf = (float*)(w + 22020096);          // 37748736 B
  short* Qhi  = (short*)(w + 59768832);
  short* Qlo  = Qhi + 3145728;
  short* KChi = Qlo + 3145728;
  short* KClo = KChi + 3145728;                  // ws end: 84934656 B
  // aliases (lifetime-disjoint)
  short* Vt = xhi;                               // after k_gemm128(qkv), x splits dead (single bf16)
  float* Wfold = (float*)Wthi;                   // Wt dead after qkv gemm (1152 B)
  float* Qm = (float*)((char*)Wthi + 8192);      // 196608 B
  float* Km = (float*)((char*)Wthi + 8192 + 196608);
  float2* stats = (float2*)((char*)qkvf + 12582912);   // qkvf dead after k_qkv_post

  short* ohi = Qhi;                              // after k_scores, Q splits dead
  short* olo = Qlo;

  k_prep<<<dim3(3840), 256, 0, stream>>>(x, xhi, xlo, W_qkv, Wthi, Wtlo, W_proj, Wpthi, Wptlo);
  k_gemm128<<<dim3(18, 32), 256, 0, stream>>>(xhi, xlo, Wthi, Wtlo, b_qkv, qkvf, 4096, 2304, 768);
  k_fold<<<dim3(1), 256, 0, stream>>>(W_conv, scale, riem, Wfold);
  k_qkv_post<<<dim3(32, 12, 4), 256, 0, stream>>>(qkvf, Qhi, Qlo, KChi, KClo, Vt, Qm, Km);
  k_scores<<<dim3(32, 16, 4), 256, 0, stream>>>(Qhi, Qlo, KChi, KClo, Qm, Km, Wfold, attn_out, stats);
  k_pvsm<<<dim3(16, 12, 4), 256, 0, stream>>>(attn_out, stats, Vt, ohi, olo);
  k_gemm<<<dim3(12, 32), 256, 0, stream>>>(ohi, olo, Wpthi, Wptlo, b_proj, out_final, 4096, 768, 768);
}

// Round 17
// 312.993 us; speedup vs baseline: 1.1930x; 1.1132x over previous
//
#include <hip/hip_runtime.h>
#include <cstddef>
#include <cstdint>

#define B_ 4
#define N_ 1024
#define C_ 768
#define H_ 12
#define D_ 64

typedef __attribute__((ext_vector_type(8))) short bf16x8;
typedef __attribute__((ext_vector_type(4))) short s16x4;
typedef __attribute__((ext_vector_type(4))) float f32x4;
typedef __attribute__((ext_vector_type(2))) float f32x2;

#define MFMA16(a_, b_, c_) __builtin_amdgcn_mfma_f32_16x16x32_bf16((a_), (b_), (c_), 0, 0, 0)
#define GLLDS16(gp_, lp_) __builtin_amdgcn_global_load_lds( \
    (const __attribute__((address_space(1))) unsigned int*)(gp_), \
    (__attribute__((address_space(3))) unsigned int*)(lp_), 16, 0, 0)

__device__ __forceinline__ unsigned short f2bf(float f) {
  unsigned int u = __float_as_uint(f);
  u += 0x7fffu + ((u >> 16) & 1u);
  return (unsigned short)(u >> 16);
}
__device__ __forceinline__ float bf2f(unsigned short b) {
  return __uint_as_float(((unsigned int)b) << 16);
}
__device__ __forceinline__ short f2h(float f) {
  _Float16 h = (_Float16)f;
  short s;
  __builtin_memcpy(&s, &h, 2);
  return s;
}
__device__ __forceinline__ float h2f(short s) {
  _Float16 h;
  __builtin_memcpy(&h, &s, 2);
  return (float)h;
}

// ---------------- fused prep: split x + split/transpose both weight matrices ----------------
__global__ __launch_bounds__(256) void k_prep(const float* __restrict__ x,
                                              short* __restrict__ xhi, short* __restrict__ xlo,
                                              const float* __restrict__ Wq,
                                              short* __restrict__ Wthi, short* __restrict__ Wtlo,
                                              const float* __restrict__ Wp,
                                              short* __restrict__ Wpthi, short* __restrict__ Wptlo) {
  __shared__ float tile[32][33];
  const int f = blockIdx.x;
  const int t = threadIdx.x;
  if (f < 1536) {
    const size_t i = ((size_t)f * 256 + t) * 8;
    float4 a = *reinterpret_cast<const float4*>(&x[i]);
    float4 b = *reinterpret_cast<const float4*>(&x[i + 4]);
    float v[8] = {a.x, a.y, a.z, a.w, b.x, b.y, b.z, b.w};
    bf16x8 hi, lo;
#pragma unroll
    for (int j = 0; j < 8; ++j) {
      unsigned short h = f2bf(v[j]);
      hi[j] = (short)h;
      lo[j] = (short)f2bf(v[j] - bf2f(h));
    }
    *reinterpret_cast<bf16x8*>(&xhi[i]) = hi;
    *reinterpret_cast<bf16x8*>(&xlo[i]) = lo;
    return;
  }
  const float* W;
  short *Thi, *Tlo;
  int Kd, Nn, bx, by;
  if (f < 3264) {
    const int local = f - 1536;
    W = Wq; Thi = Wthi; Tlo = Wtlo; Kd = 768; Nn = 2304;
    bx = local % 72; by = local / 72;
  } else {
    const int local = f - 3264;
    W = Wp; Thi = Wpthi; Tlo = Wptlo; Kd = 768; Nn = 768;
    bx = local % 24; by = local / 24;
  }
  const int k0 = by * 32, n0 = bx * 32;
  const int r = t >> 3, cq = (t & 7) * 4;
  float4 v = *reinterpret_cast<const float4*>(&W[(size_t)(k0 + r) * Nn + n0 + cq]);
  tile[r][cq + 0] = v.x; tile[r][cq + 1] = v.y;
  tile[r][cq + 2] = v.z; tile[r][cq + 3] = v.w;
  __syncthreads();
  const int nrow = t >> 3, kq = (t & 7) * 4;
  s16x4 hi, lo;
#pragma unroll
  for (int i = 0; i < 4; ++i) {
    float fv = tile[kq + i][nrow];
    unsigned short h = f2bf(fv);
    hi[i] = (short)h;
    lo[i] = (short)f2bf(fv - bf2f(h));
  }
  *reinterpret_cast<s16x4*>(&Thi[(size_t)(n0 + nrow) * Kd + k0 + kq]) = hi;
  *reinterpret_cast<s16x4*>(&Tlo[(size_t)(n0 + nrow) * Kd + k0 + kq]) = lo;
}

// ---------------- fold scale/riem into W_conv ----------------
__global__ __launch_bounds__(256) void k_fold(const float* __restrict__ Wc,
                                              const float* __restrict__ scale_p,
                                              const float* __restrict__ riem_p,
                                              float* __restrict__ Wfold) {
  const int t = threadIdx.x;
  const float scale = scale_p[0], riem = riem_p[0];
  for (int i = t; i < 288; i += 256)
    Wfold[i] = Wc[i] * (((i % 24) < 12) ? scale : riem);
}

// ---------------- split-bf16 MFMA GEMM, BM=128 BN=64 BK=32 (for proj) ----------------
__global__ __launch_bounds__(256) void k_gemm(const short* __restrict__ Ahi,
                                              const short* __restrict__ Alo,
                                              const short* __restrict__ Bhi,
                                              const short* __restrict__ Blo,
                                              const float* __restrict__ bias,
                                              float* __restrict__ Cout,
                                              int M, int Nn, int Kd) {
  __shared__ __align__(16) short sA[2][128 * 32];
  __shared__ __align__(16) short sB[2][64 * 32];
  const int tid = threadIdx.x;
  const int wv = tid >> 6, l = tid & 63;
  const int lr = l & 15, lg = l >> 4;
  const int row0 = blockIdx.y * 128;
  const int col0 = blockIdx.x * 64;
  const int wr = (wv >> 1) * 64;
  const int wc = (wv & 1) * 32;
  const int ar = tid >> 2, ac = tid & 3;
  f32x4 acc[4][2];
#pragma unroll
  for (int i = 0; i < 4; ++i)
#pragma unroll
    for (int j = 0; j < 2; ++j) acc[i][j] = (f32x4){0.f, 0.f, 0.f, 0.f};

  for (int k0 = 0; k0 < Kd; k0 += 32) {
#pragma unroll
    for (int j = 0; j < 2; ++j) {
      const int row = j * 64 + ar;
      const int cc = ac ^ ((row >> 1) & 3);
      const size_t so = (size_t)(row0 + row) * Kd + k0 + cc * 8;
      GLLDS16(Ahi + so, &sA[0][(j * 256 + (wv << 6)) * 8]);
      GLLDS16(Alo + so, &sA[1][(j * 256 + (wv << 6)) * 8]);
    }
    {
      const int row = ar;
      const int cc = ac ^ ((row >> 1) & 3);
      const size_t so = (size_t)(col0 + row) * Kd + k0 + cc * 8;
      GLLDS16(Bhi + so, &sB[0][(wv << 6) * 8]);
      GLLDS16(Blo + so, &sB[1][(wv << 6) * 8]);
    }
    __syncthreads();
    bf16x8 afh[4], afl[4], bfh[2], bfl[2];
#pragma unroll
    for (int ti = 0; ti < 4; ++ti) {
      const int row = wr + ti * 16 + lr;
      const int pc = lg ^ ((row >> 1) & 3);
      afh[ti] = *reinterpret_cast<const bf16x8*>(&sA[0][row * 32 + pc * 8]);
      afl[ti] = *reinterpret_cast<const bf16x8*>(&sA[1][row * 32 + pc * 8]);
    }
#pragma unroll
    for (int tj = 0; tj < 2; ++tj) {
      const int row = wc + tj * 16 + lr;
      const int pc = lg ^ ((row >> 1) & 3);
      bfh[tj] = *reinterpret_cast<const bf16x8*>(&sB[0][row * 32 + pc * 8]);
      bfl[tj] = *reinterpret_cast<const bf16x8*>(&sB[1][row * 32 + pc * 8]);
    }
#pragma unroll
    for (int ti = 0; ti < 4; ++ti)
#pragma unroll
      for (int tj = 0; tj < 2; ++tj) {
        acc[ti][tj] = MFMA16(afh[ti], bfh[tj], acc[ti][tj]);
        acc[ti][tj] = MFMA16(afl[ti], bfh[tj], acc[ti][tj]);
        acc[ti][tj] = MFMA16(afh[ti], bfl[tj], acc[ti][tj]);
      }
    __syncthreads();
  }
#pragma unroll
  for (int ti = 0; ti < 4; ++ti)
#pragma unroll
    for (int tj = 0; tj < 2; ++tj) {
      const int col = col0 + wc + tj * 16 + lr;
      const float bb = bias[col];
#pragma unroll
      for (int r = 0; r < 4; ++r) {
        const int row = row0 + wr + ti * 16 + lg * 4 + r;
        Cout[(size_t)row * Nn + col] = acc[ti][tj][r] + bb;
      }
    }
}

// ---------------- split-bf16 MFMA GEMM, BM=128 BN=128 BK=32 (for qkv) ----------------
__global__ __launch_bounds__(256) void k_gemm128(const short* __restrict__ Ahi,
                                                 const short* __restrict__ Alo,
                                                 const short* __restrict__ Bhi,
                                                 const short* __restrict__ Blo,
                                                 const float* __restrict__ bias,
                                                 float* __restrict__ Cout,
                                                 int M, int Nn, int Kd) {
  __shared__ __align__(16) short sA[2][128 * 32];
  __shared__ __align__(16) short sB[2][128 * 32];
  const int tid = threadIdx.x;
  const int wv = tid >> 6, l = tid & 63;
  const int lr = l & 15, lg = l >> 4;
  const int row0 = blockIdx.y * 128;
  const int col0 = blockIdx.x * 128;
  const int wr = (wv >> 1) * 64;
  const int wc = (wv & 1) * 64;
  const int ar = tid >> 2, ac = tid & 3;
  f32x4 acc[4][4];
#pragma unroll
  for (int i = 0; i < 4; ++i)
#pragma unroll
    for (int j = 0; j < 4; ++j) acc[i][j] = (f32x4){0.f, 0.f, 0.f, 0.f};

  for (int k0 = 0; k0 < Kd; k0 += 32) {
#pragma unroll
    for (int j = 0; j < 2; ++j) {
      const int row = j * 64 + ar;
      const int cc = ac ^ ((row >> 1) & 3);
      const size_t ao = (size_t)(row0 + row) * Kd + k0 + cc * 8;
      const size_t bo = (size_t)(col0 + row) * Kd + k0 + cc * 8;
      GLLDS16(Ahi + ao, &sA[0][(j * 256 + (wv << 6)) * 8]);
      GLLDS16(Alo + ao, &sA[1][(j * 256 + (wv << 6)) * 8]);
      GLLDS16(Bhi + bo, &sB[0][(j * 256 + (wv << 6)) * 8]);
      GLLDS16(Blo + bo, &sB[1][(j * 256 + (wv << 6)) * 8]);
    }
    __syncthreads();
    bf16x8 afh[4], afl[4], bfh[4], bfl[4];
#pragma unroll
    for (int ti = 0; ti < 4; ++ti) {
      const int row = wr + ti * 16 + lr;
      const int pc = lg ^ ((row >> 1) & 3);
      afh[ti] = *reinterpret_cast<const bf16x8*>(&sA[0][row * 32 + pc * 8]);
      afl[ti] = *reinterpret_cast<const bf16x8*>(&sA[1][row * 32 + pc * 8]);
    }
#pragma unroll
    for (int tj = 0; tj < 4; ++tj) {
      const int row = wc + tj * 16 + lr;
      const int pc = lg ^ ((row >> 1) & 3);
      bfh[tj] = *reinterpret_cast<const bf16x8*>(&sB[0][row * 32 + pc * 8]);
      bfl[tj] = *reinterpret_cast<const bf16x8*>(&sB[1][row * 32 + pc * 8]);
    }
#pragma unroll
    for (int ti = 0; ti < 4; ++ti)
#pragma unroll
      for (int tj = 0; tj < 4; ++tj) {
        acc[ti][tj] = MFMA16(afh[ti], bfh[tj], acc[ti][tj]);
        acc[ti][tj] = MFMA16(afl[ti], bfh[tj], acc[ti][tj]);
        acc[ti][tj] = MFMA16(afh[ti], bfl[tj], acc[ti][tj]);
      }
    __syncthreads();
  }
#pragma unroll
  for (int ti = 0; ti < 4; ++ti)
#pragma unroll
    for (int tj = 0; tj < 4; ++tj) {
      const int col = col0 + wc + tj * 16 + lr;
      const float bb = bias[col];
#pragma unroll
      for (int r = 0; r < 4; ++r) {
        const int row = row0 + wr + ti * 16 + lg * 4 + r;
        Cout[(size_t)row * Nn + col] = acc[ti][tj][r] + bb;
      }
    }
}

// ---------------- qkv post: split Q, center+split K, means, transpose V (single bf16) ----------------
__global__ __launch_bounds__(256) void k_qkv_post(const float* __restrict__ qkvf,
                                                  short* __restrict__ Qhi, short* __restrict__ Qlo,
                                                  short* __restrict__ KChi, short* __restrict__ KClo,
                                                  short* __restrict__ Vt,
                                                  float* __restrict__ Qm, float* __restrict__ Km) {
  __shared__ unsigned short lvh[64][33];
  const int b = blockIdx.z, h = blockIdx.y, n0 = blockIdx.x * 32;
  const int t = threadIdx.x;
  const int row = t >> 3, d0 = (t & 7) * 8;
  const int n = n0 + row;
  const float* base = qkvf + ((size_t)(b * 1024 + n)) * 2304 + h * 64 + d0;
  const size_t qko = ((size_t)(b * H_ + h) * N_ + n) * D_ + d0;

#pragma unroll
  for (int part = 0; part < 2; ++part) {  // 0: q, 1: k (centered)
    float4 a = *reinterpret_cast<const float4*>(base + part * 768);
    float4 c = *reinterpret_cast<const float4*>(base + part * 768 + 4);
    float v[8] = {a.x, a.y, a.z, a.w, c.x, c.y, c.z, c.w};
    float s = v[0] + v[1] + v[2] + v[3] + v[4] + v[5] + v[6] + v[7];
#pragma unroll
    for (int off = 1; off < 8; off <<= 1) s += __shfl_xor(s, off);
    const float mean = s * (1.0f / 64.0f);
    if ((t & 7) == 0) (part ? Km : Qm)[(size_t)(b * H_ + h) * N_ + n] = mean;
    const float sub = part ? mean : 0.0f;
    bf16x8 hi, lo;
#pragma unroll
    for (int j = 0; j < 8; ++j) {
      const float fv = v[j] - sub;
      unsigned short hh = f2bf(fv);
      hi[j] = (short)hh;
      lo[j] = (short)f2bf(fv - bf2f(hh));
    }
    *reinterpret_cast<bf16x8*>((part ? KChi : Qhi) + qko) = hi;
    *reinterpret_cast<bf16x8*>((part ? KClo : Qlo) + qko) = lo;
  }
  {  // v -> transposed single bf16
    float4 a = *reinterpret_cast<const float4*>(base + 1536);
    float4 c = *reinterpret_cast<const float4*>(base + 1536 + 4);
    float v[8] = {a.x, a.y, a.z, a.w, c.x, c.y, c.z, c.w};
#pragma unroll
    for (int j = 0; j < 8; ++j) lvh[d0 + j][row] = f2bf(v[j]);
  }
  __syncthreads();
  const int d = t >> 2, c = t & 3;
  bf16x8 vh;
#pragma unroll
  for (int i = 0; i < 8; ++i) vh[i] = (short)lvh[d][c * 8 + i];
  const size_t vo = ((size_t)(b * H_ + h) * D_ + d) * N_ + n0 + c * 8;
  *reinterpret_cast<bf16x8*>(Vt + vo) = vh;
}

// ---------------- scores + channel mix -> f16 RESIDUAL logits (+ per-block softmax stats) ----------------
// 64n x 32m block. Stores (logit - M_seg) as f16 into the LOW half of each attn
// row's f32 slot; stats (M_seg, S_seg) as before. k_pvsm expands in-place.
__global__ __launch_bounds__(256, 2) void k_scores(
    const short* __restrict__ Qhi, const short* __restrict__ Qlo,
    const short* __restrict__ KChi, const short* __restrict__ KClo,
    const float* __restrict__ Qm, const float* __restrict__ Km,
    const float* __restrict__ Wfold, float* __restrict__ logits,
    float2* __restrict__ stats) {
  __shared__ __align__(16) short sCh[2][32 * 64];
  __shared__ __align__(16) short sCl[2][32 * 64];
  __shared__ float sQm[12][64];
  __shared__ float sKm[12][32];

  const int t = threadIdx.x;
  const int b = blockIdx.z;
  const int n0 = blockIdx.y * 64, m0 = blockIdx.x * 32;
  const int wv = t >> 6, l = t & 63;
  const int lr = l & 15, lg = l >> 4;
  const size_t bh0 = (size_t)b * H_;

  for (int i = t; i < 768; i += 256)
    sQm[i >> 6][i & 63] = Qm[(bh0 + (i >> 6)) * N_ + n0 + (i & 63)];
  for (int i = t; i < 384; i += 256)
    sKm[i >> 5][i & 31] = Km[(bh0 + (i >> 5)) * N_ + m0 + (i & 31)];

  const int srow = t >> 3;
  const int scs = (t & 7) ^ (srow & 7);
  const size_t csrc = (bh0 * N_ + m0 + srow) * D_ + scs * 8;
  const size_t hstep = (size_t)N_ * D_;
  const int nb = n0 + wv * 16;
  const size_t qsrc = (bh0 * N_ + nb + lr) * D_ + lg * 8;

  GLLDS16(KChi + csrc, &sCh[0][wv * 512]);
  GLLDS16(KClo + csrc, &sCl[0][wv * 512]);
  bf16x8 qh0 = *reinterpret_cast<const bf16x8*>(Qhi + qsrc);
  bf16x8 qh1 = *reinterpret_cast<const bf16x8*>(Qhi + qsrc + 32);
  bf16x8 ql0 = *reinterpret_cast<const bf16x8*>(Qlo + qsrc);
  bf16x8 ql1 = *reinterpret_cast<const bf16x8*>(Qlo + qsrc + 32);

  f32x2 aA01[12], aA23[12], aB01[12], aB23[12];
#pragma unroll
  for (int o = 0; o < 12; ++o) {
    aA01[o] = (f32x2){0.f, 0.f}; aA23[o] = (f32x2){0.f, 0.f};
    aB01[o] = (f32x2){0.f, 0.f}; aB23[o] = (f32x2){0.f, 0.f};
  }

  const int browA = lr, browB = 16 + lr;
  const int aiA0 = browA * 64 + ((lg + 0) ^ (browA & 7)) * 8;
  const int aiA1 = browA * 64 + ((lg + 4) ^ (browA & 7)) * 8;
  const int aiB0 = browB * 64 + ((lg + 0) ^ (browB & 7)) * 8;
  const int aiB1 = browB * 64 + ((lg + 4) ^ (browB & 7)) * 8;
  __syncthreads();

  int buf = 0;
#pragma unroll 2
  for (int h = 0; h < H_; ++h) {
    bf16x8 nqh0, nqh1, nql0, nql1;
    if (h < 11) {
      const size_t cs = csrc + (size_t)(h + 1) * hstep;
      GLLDS16(KChi + cs, &sCh[buf ^ 1][wv * 512]);
      GLLDS16(KClo + cs, &sCl[buf ^ 1][wv * 512]);
      const size_t qs = qsrc + (size_t)(h + 1) * hstep;
      nqh0 = *reinterpret_cast<const bf16x8*>(Qhi + qs);
      nqh1 = *reinterpret_cast<const bf16x8*>(Qhi + qs + 32);
      nql0 = *reinterpret_cast<const bf16x8*>(Qlo + qs);
      nql1 = *reinterpret_cast<const bf16x8*>(Qlo + qs + 32);
    }
    const bf16x8 chA0 = *reinterpret_cast<const bf16x8*>(&sCh[buf][aiA0]);
    const bf16x8 chA1 = *reinterpret_cast<const bf16x8*>(&sCh[buf][aiA1]);
    const bf16x8 clA0 = *reinterpret_cast<const bf16x8*>(&sCl[buf][aiA0]);
    const bf16x8 clA1 = *reinterpret_cast<const bf16x8*>(&sCl[buf][aiA1]);
    const bf16x8 chB0 = *reinterpret_cast<const bf16x8*>(&sCh[buf][aiB0]);
    const bf16x8 chB1 = *reinterpret_cast<const bf16x8*>(&sCh[buf][aiB1]);
    const bf16x8 clB0 = *reinterpret_cast<const bf16x8*>(&sCl[buf][aiB0]);
    const bf16x8 clB1 = *reinterpret_cast<const bf16x8*>(&sCl[buf][aiB1]);

    f32x4 uaA = {0.f, 0.f, 0.f, 0.f}, ubA = {0.f, 0.f, 0.f, 0.f};
    f32x4 uaB = {0.f, 0.f, 0.f, 0.f}, ubB = {0.f, 0.f, 0.f, 0.f};
    uaA = MFMA16(qh0, chA0, uaA);  ubA = MFMA16(qh1, chA1, ubA);
    uaB = MFMA16(qh0, chB0, uaB);  ubB = MFMA16(qh1, chB1, ubB);
    uaA = MFMA16(qh0, clA0, uaA);  ubA = MFMA16(qh1, clA1, ubA);
    uaB = MFMA16(qh0, clB0, uaB);  ubB = MFMA16(qh1, clB1, ubB);
    uaA = MFMA16(ql0, chA0, uaA);  ubA = MFMA16(ql1, chA1, ubA);
    uaB = MFMA16(ql0, chB0, uaB);  ubB = MFMA16(ql1, chB1, ubB);

    const float4 qm4 = *reinterpret_cast<const float4*>(&sQm[h][wv * 16 + lg * 4]);
    const float kmA = 64.0f * sKm[h][lr];
    const float kmB = 64.0f * sKm[h][16 + lr];
    const f32x2 qm01 = {qm4.x, qm4.y};
    const f32x2 qm23 = {qm4.z, qm4.w};
    const f32x2 uA01 = {uaA[0] + ubA[0], uaA[1] + ubA[1]};
    const f32x2 uA23 = {uaA[2] + ubA[2], uaA[3] + ubA[3]};
    const f32x2 uB01 = {uaB[0] + ubB[0], uaB[1] + ubB[1]};
    const f32x2 uB23 = {uaB[2] + ubB[2], uaB[3] + ubB[3]};
    const f32x2 svA01 = kmA * qm01 + uA01;
    const f32x2 svA23 = kmA * qm23 + uA23;
    const f32x2 svB01 = kmB * qm01 + uB01;
    const f32x2 svB23 = kmB * qm23 + uB23;
    const f32x2 u2A01 = uA01 * uA01;
    const f32x2 u2A23 = uA23 * uA23;
    const f32x2 u2B01 = uB01 * uB01;
    const f32x2 u2B23 = uB23 * uB23;
#pragma unroll
    for (int o = 0; o < 12; ++o) {
      const float we = Wfold[o * 24 + h];
      const float wr = Wfold[o * 24 + 12 + h];
      aA01[o] = aA01[o] + we * svA01 + wr * u2A01;
      aA23[o] = aA23[o] + we * svA23 + wr * u2A23;
      aB01[o] = aB01[o] + we * svB01 + wr * u2B01;
      aB23[o] = aB23[o] + we * svB23 + wr * u2B23;
    }
    __syncthreads();
    buf ^= 1;
    if (h < 11) { qh0 = nqh0; qh1 = nqh1; ql0 = nql0; ql1 = nql1; }
  }

  // epilogue: per-o segment max/sum, then f16 residual writes + stats
#pragma unroll
  for (int o = 0; o < 12; ++o) {
    float avA[4] = {aA01[o][0], aA01[o][1], aA23[o][0], aA23[o][1]};
    float avB[4] = {aB01[o][0], aB01[o][1], aB23[o][0], aB23[o][1]};
    float M4[4], S4[4];
#pragma unroll
    for (int r = 0; r < 4; ++r) {
      float mxA = avA[r], mxB = avB[r];
      mxA = fmaxf(mxA, __shfl_xor(mxA, 1)); mxB = fmaxf(mxB, __shfl_xor(mxB, 1));
      mxA = fmaxf(mxA, __shfl_xor(mxA, 2)); mxB = fmaxf(mxB, __shfl_xor(mxB, 2));
      mxA = fmaxf(mxA, __shfl_xor(mxA, 4)); mxB = fmaxf(mxB, __shfl_xor(mxB, 4));
      mxA = fmaxf(mxA, __shfl_xor(mxA, 8)); mxB = fmaxf(mxB, __shfl_xor(mxB, 8));
      const float M = fmaxf(mxA, mxB);
      float eA = __expf(avA[r] - M);
      float eB = __expf(avB[r] - M);
      float e = eA + eB;
      e += __shfl_xor(e, 1);
      e += __shfl_xor(e, 2);
      e += __shfl_xor(e, 4);
      e += __shfl_xor(e, 8);
      M4[r] = M; S4[r] = e;
    }
#pragma unroll
    for (int r = 0; r < 4; ++r) {
      short* rowp = (short*)(logits + ((bh0 + o) * N_ + nb + lg * 4 + r) * (size_t)N_);
      rowp[m0 + lr] = f2h(avA[r] - M4[r]);
      rowp[m0 + 16 + lr] = f2h(avB[r] - M4[r]);
    }
    if (lr < 4) {
      const int n = nb + lg * 4 + lr;
      stats[(((size_t)b * 12 + o) * 32 + blockIdx.x) * 1024 + n] = make_float2(M4[lr], S4[lr]);
    }
  }
}

// ---------------- fused stats-merge + softmax-expand (f16 residual -> f32 in-place)
// + PV MFMA (64n x 64m, bf16 V dbuf, DESCENDING m-chunks for in-place safety) ----------------
__global__ __launch_bounds__(256) void k_pvsm(float* __restrict__ attn,
                                              const float2* __restrict__ stats,
                                              const short* __restrict__ Vt,
                                              short* __restrict__ ohi,
                                              short* __restrict__ olo) {
  __shared__ __align__(16) short sPhi[64 * 64];
  __shared__ __align__(16) short sPlo[64 * 64];
  __shared__ __align__(16) short sV[2][64 * 64];
  __shared__ float sIS[64];
  __shared__ short sMseg16[64 * 32];  // f16(M_seg - M_global) per row
  // XCD swizzle: flat (x + y*16 + z*192) in [0,768); 768 % 8 == 0 -> bijective
  const int flat = blockIdx.x + blockIdx.y * 16 + blockIdx.z * 192;
  const int swz = (flat & 7) * 96 + (flat >> 3);
  const int b = swz / 192;
  const int rem = swz - b * 192;
  const int o = rem >> 4;
  const int n0 = (rem & 15) * 64;
  const int bo = b * H_ + o;
  const int t = threadIdx.x;
  const int wv = t >> 6, l = t & 63;
  const int lr = l & 15, lg = l >> 4;
  const int nsub = wv * 16;

  const int vr0 = t >> 3, vr1 = vr0 + 32;
  const int vc0 = (t & 7) ^ (vr0 & 7);
  const int vc1 = (t & 7) ^ (vr1 & 7);
  const size_t vbase = (size_t)bo * D_ * N_;
  const size_t vs0 = vbase + (size_t)vr0 * N_ + vc0 * 8;
  const size_t vs1 = vbase + (size_t)vr1 * N_ + vc1 * 8;

  // stage LAST chunk (mc=15) into sV[1]
  GLLDS16(Vt + vs0 + 960, &sV[1][(wv * 64) * 8]);
  GLLDS16(Vt + vs1 + 960, &sV[1][(wv * 64 + 256) * 8]);

  // merge partial stats for this block's 64 rows; store per-seg f16 offsets
  if (t < 64) {
    const int n = n0 + t;
    const float2* sp = stats + ((size_t)bo * 32) * 1024 + n;
    float M = -3.0e38f, S = 0.f;
    for (int seg = 0; seg < 32; ++seg) {
      const float2 p = sp[(size_t)seg * 1024];
      if (p.x > M) {
        S = S * __expf(M - p.x) + p.y;
        M = p.x;
      } else {
        S += p.y * __expf(p.x - M);
      }
    }
    sIS[t] = 1.0f / S;
    for (int seg = 0; seg < 32; ++seg)
      sMseg16[t * 32 + seg] = f2h(sp[(size_t)seg * 1024].x - M);
  }

  const int prow = t >> 3, c0 = (t & 7) * 8;
  float* lrowA = attn + ((size_t)bo * N_ + n0 + prow) * N_;
  float* lrowB = attn + ((size_t)bo * N_ + n0 + prow + 32) * N_;
  const int pofsA = prow * 64 + (((t & 7) ^ (prow & 7)) * 8);
  const int pofsB = pofsA + 32 * 64;

  const int arow = nsub + lr;
  const int ai0 = arow * 64 + (((lg + 0) ^ (arow & 7)) * 8);
  const int ai1 = arow * 64 + (((lg + 4) ^ (arow & 7)) * 8);

  f32x4 acc[4];
#pragma unroll
  for (int dt = 0; dt < 4; ++dt) acc[dt] = (f32x4){0.f, 0.f, 0.f, 0.f};
  __syncthreads();

  for (int mc = 15; mc >= 0; --mc) {
    const int m0 = mc * 64;
    if (mc > 0) {  // prefetch PREVIOUS chunk (descending)
      const int nb2 = (mc - 1) & 1;
      GLLDS16(Vt + vs0 + m0 - 64, &sV[nb2][(wv * 64) * 8]);
      GLLDS16(Vt + vs1 + m0 - 64, &sV[nb2][(wv * 64 + 256) * 8]);
    }
    // f16 residual reads + expand
    const int sidx = mc * 2 + ((t & 7) >> 2);
    const float ofsA = h2f(sMseg16[prow * 32 + sidx]);
    const float ofsB = h2f(sMseg16[(prow + 32) * 32 + sidx]);
    const float iSA = sIS[prow], iSB = sIS[prow + 32];
    const bf16x8 rA = *reinterpret_cast<const bf16x8*>(&((const short*)lrowA)[m0 + c0]);
    const bf16x8 rB = *reinterpret_cast<const bf16x8*>(&((const short*)lrowB)[m0 + c0]);
    float pA[8], pB[8];
#pragma unroll
    for (int j = 0; j < 8; ++j) {
      pA[j] = __expf(h2f(rA[j]) + ofsA) * iSA;
      pB[j] = __expf(h2f(rB[j]) + ofsB) * iSB;
    }
    bf16x8 phiA, ploA, phiB, ploB;
#pragma unroll
    for (int j = 0; j < 8; ++j) {
      unsigned short hA = f2bf(pA[j]);
      phiA[j] = (short)hA;
      ploA[j] = (short)f2bf(pA[j] - bf2f(hA));
      unsigned short hB = f2bf(pB[j]);
      phiB[j] = (short)hB;
      ploB[j] = (short)f2bf(pB[j] - bf2f(hB));
    }
    *reinterpret_cast<bf16x8*>(&sPhi[pofsA]) = phiA;
    *reinterpret_cast<bf16x8*>(&sPlo[pofsA]) = ploA;
    *reinterpret_cast<bf16x8*>(&sPhi[pofsB]) = phiB;
    *reinterpret_cast<bf16x8*>(&sPlo[pofsB]) = ploB;
    __syncthreads();  // all f16 reads of this chunk complete block-wide

    // in-place f32 attn write (safe: descending chunks + post-barrier)
    float4 oaA = {pA[0], pA[1], pA[2], pA[3]};
    float4 obA = {pA[4], pA[5], pA[6], pA[7]};
    float4 oaB = {pB[0], pB[1], pB[2], pB[3]};
    float4 obB = {pB[4], pB[5], pB[6], pB[7]};
    *reinterpret_cast<float4*>(&lrowA[m0 + c0]) = oaA;
    *reinterpret_cast<float4*>(&lrowA[m0 + c0 + 4]) = obA;
    *reinterpret_cast<float4*>(&lrowB[m0 + c0]) = oaB;
    *reinterpret_cast<float4*>(&lrowB[m0 + c0 + 4]) = obB;

    const int cur = mc & 1;
    const bf16x8 pah0 = *reinterpret_cast<const bf16x8*>(&sPhi[ai0]);
    const bf16x8 pah1 = *reinterpret_cast<const bf16x8*>(&sPhi[ai1]);
    const bf16x8 pal0 = *reinterpret_cast<const bf16x8*>(&sPlo[ai0]);
    const bf16x8 pal1 = *reinterpret_cast<const bf16x8*>(&sPlo[ai1]);
#pragma unroll
    for (int dt = 0; dt < 4; ++dt) {
      const int drow = dt * 16 + lr;
      const bf16x8 vh0 = *reinterpret_cast<const bf16x8*>(&sV[cur][drow * 64 + (((lg + 0) ^ (drow & 7)) * 8)]);
      const bf16x8 vh1 = *reinterpret_cast<const bf16x8*>(&sV[cur][drow * 64 + (((lg + 4) ^ (drow & 7)) * 8)]);
      acc[dt] = MFMA16(pah0, vh0, acc[dt]);
      acc[dt] = MFMA16(pal0, vh0, acc[dt]);
      acc[dt] = MFMA16(pah1, vh1, acc[dt]);
      acc[dt] = MFMA16(pal1, vh1, acc[dt]);
    }
    __syncthreads();
  }
#pragma unroll
  for (int dt = 0; dt < 4; ++dt) {
    const int d = dt * 16 + lr;
#pragma unroll
    for (int r = 0; r < 4; ++r) {
      const int n = n0 + nsub + lg * 4 + r;
      const float val = acc[dt][r];
      const unsigned short hh = f2bf(val);
      const size_t oo = (size_t)(b * 1024 + n) * 768 + o * 64 + d;
      ohi[oo] = (short)hh;
      olo[oo] = (short)f2bf(val - bf2f(hh));
    }
  }
}

extern "C" void kernel_launch(void* const* d_in, const int* in_sizes, int n_in,
                              void* d_out, int out_size, void* d_ws, size_t ws_size,
                              hipStream_t stream) {
  (void)in_sizes; (void)n_in; (void)out_size; (void)ws_size;
  const float* x      = (const float*)d_in[0];
  const float* W_qkv  = (const float*)d_in[1];
  const float* b_qkv  = (const float*)d_in[2];
  const float* scale  = (const float*)d_in[3];
  const float* riem   = (const float*)d_in[4];
  const float* W_conv = (const float*)d_in[5];
  // d_in[6] = b_conv: constant along softmax axis -> softmax-invariant, skipped
  const float* W_proj = (const float*)d_in[7];
  const float* b_proj = (const float*)d_in[8];

  float* out_final = (float*)d_out;                     // [B,N,C]
  float* attn_out  = out_final + (size_t)B_ * N_ * C_;  // [B,H,N,N] f16 residuals -> f32 attn in-place

  char* w = (char*)d_ws;
  short* xhi  = (short*)w;                       // 6291456 B
  short* xlo  = xhi + 3145728;                   // 6291456 B
  short* Wthi = (short*)(w + 12582912);          // 3538944 B
  short* Wtlo = Wthi + 1769472;                  // 3538944 B
  short* Wpthi = (short*)(w + 19660800);         // 1179648 B
  short* Wptlo = Wpthi + 589824;                 // 1179648 B
  float* qkvf = (float*)(w + 22020096);          // 37748736 B
  short* Qhi  = (short*)(w + 59768832);
  short* Qlo  = Qhi + 3145728;
  short* KChi = Qlo + 3145728;
  short* KClo = KChi + 3145728;                  // ws end: 84934656 B
  // aliases (lifetime-disjoint)
  short* Vt = xhi;                               // after k_gemm128(qkv), x splits dead (single bf16)
  float* Wfold = (float*)Wthi;                   // Wt dead after qkv gemm (1152 B)
  float* Qm = (float*)((char*)Wthi + 8192);      // 196608 B
  float* Km = (float*)((char*)Wthi + 8192 + 196608);
  float2* stats = (float2*)((char*)qkvf + 12582912);   // qkvf dead after k_qkv_post

  short* ohi = Qhi;                              // after k_scores, Q splits dead
  short* olo = Qlo;

  k_prep<<<dim3(3840), 256, 0, stream>>>(x, xhi, xlo, W_qkv, Wthi, Wtlo, W_proj, Wpthi, Wptlo);
  k_gemm128<<<dim3(18, 32), 256, 0, stream>>>(xhi, xlo, Wthi, Wtlo, b_qkv, qkvf, 4096, 2304, 768);
  k_fold<<<dim3(1), 256, 0, stream>>>(W_conv, scale, riem, Wfold);
  k_qkv_post<<<dim3(32, 12, 4), 256, 0, stream>>>(qkvf, Qhi, Qlo, KChi, KClo, Vt, Qm, Km);
  k_scores<<<dim3(32, 16, 4), 256, 0, stream>>>(Qhi, Qlo, KChi, KClo, Qm, Km, Wfold, attn_out, stats);
  k_pvsm<<<dim3(16, 12, 4), 256, 0, stream>>>(attn_out, stats, Vt, ohi, olo);
  k_gemm<<<dim3(12, 32), 256, 0, stream>>>(ohi, olo, Wpthi, Wptlo, b_proj, out_final, 4096, 768, 768);
}

// Round 18
// 299.134 us; speedup vs baseline: 1.2483x; 1.0463x over previous
//
#include <hip/hip_runtime.h>
#include <cstddef>
#include <cstdint>

#define B_ 4
#define N_ 1024
#define C_ 768
#define H_ 12
#define D_ 64

typedef __attribute__((ext_vector_type(8))) short bf16x8;
typedef __attribute__((ext_vector_type(4))) short s16x4;
typedef __attribute__((ext_vector_type(4))) float f32x4;
typedef __attribute__((ext_vector_type(2))) float f32x2;

#define MFMA16(a_, b_, c_) __builtin_amdgcn_mfma_f32_16x16x32_bf16((a_), (b_), (c_), 0, 0, 0)
#define GLLDS16(gp_, lp_) __builtin_amdgcn_global_load_lds( \
    (const __attribute__((address_space(1))) unsigned int*)(gp_), \
    (__attribute__((address_space(3))) unsigned int*)(lp_), 16, 0, 0)

__device__ __forceinline__ unsigned short f2bf(float f) {
  unsigned int u = __float_as_uint(f);
  u += 0x7fffu + ((u >> 16) & 1u);
  return (unsigned short)(u >> 16);
}
__device__ __forceinline__ float bf2f(unsigned short b) {
  return __uint_as_float(((unsigned int)b) << 16);
}
__device__ __forceinline__ short f2h(float f) {
  _Float16 h = (_Float16)f;
  short s;
  __builtin_memcpy(&s, &h, 2);
  return s;
}
__device__ __forceinline__ float h2f(short s) {
  _Float16 h;
  __builtin_memcpy(&h, &s, 2);
  return (float)h;
}

// ---------------- fused prep: split x + split/transpose weights + fold W_conv ----------------
// blocks [0,1536): split_x; [1536,3264): split_T(W_qkv); [3264,3840): split_T(W_proj);
// block 3840: fold scale/riem into W_conv.
__global__ __launch_bounds__(256) void k_prep(const float* __restrict__ x,
                                              short* __restrict__ xhi, short* __restrict__ xlo,
                                              const float* __restrict__ Wq,
                                              short* __restrict__ Wthi, short* __restrict__ Wtlo,
                                              const float* __restrict__ Wp,
                                              short* __restrict__ Wpthi, short* __restrict__ Wptlo,
                                              const float* __restrict__ Wc,
                                              const float* __restrict__ scale_p,
                                              const float* __restrict__ riem_p,
                                              float* __restrict__ Wfold) {
  __shared__ float tile[32][33];
  const int f = blockIdx.x;
  const int t = threadIdx.x;
  if (f == 3840) {
    const float scale = scale_p[0], riem = riem_p[0];
    for (int i = t; i < 288; i += 256)
      Wfold[i] = Wc[i] * (((i % 24) < 12) ? scale : riem);
    return;
  }
  if (f < 1536) {
    const size_t i = ((size_t)f * 256 + t) * 8;
    float4 a = *reinterpret_cast<const float4*>(&x[i]);
    float4 b = *reinterpret_cast<const float4*>(&x[i + 4]);
    float v[8] = {a.x, a.y, a.z, a.w, b.x, b.y, b.z, b.w};
    bf16x8 hi, lo;
#pragma unroll
    for (int j = 0; j < 8; ++j) {
      unsigned short h = f2bf(v[j]);
      hi[j] = (short)h;
      lo[j] = (short)f2bf(v[j] - bf2f(h));
    }
    *reinterpret_cast<bf16x8*>(&xhi[i]) = hi;
    *reinterpret_cast<bf16x8*>(&xlo[i]) = lo;
    return;
  }
  const float* W;
  short *Thi, *Tlo;
  int Kd, Nn, bx, by;
  if (f < 3264) {
    const int local = f - 1536;
    W = Wq; Thi = Wthi; Tlo = Wtlo; Kd = 768; Nn = 2304;
    bx = local % 72; by = local / 72;
  } else {
    const int local = f - 3264;
    W = Wp; Thi = Wpthi; Tlo = Wptlo; Kd = 768; Nn = 768;
    bx = local % 24; by = local / 24;
  }
  const int k0 = by * 32, n0 = bx * 32;
  const int r = t >> 3, cq = (t & 7) * 4;
  float4 v = *reinterpret_cast<const float4*>(&W[(size_t)(k0 + r) * Nn + n0 + cq]);
  tile[r][cq + 0] = v.x; tile[r][cq + 1] = v.y;
  tile[r][cq + 2] = v.z; tile[r][cq + 3] = v.w;
  __syncthreads();
  const int nrow = t >> 3, kq = (t & 7) * 4;
  s16x4 hi, lo;
#pragma unroll
  for (int i = 0; i < 4; ++i) {
    float fv = tile[kq + i][nrow];
    unsigned short h = f2bf(fv);
    hi[i] = (short)h;
    lo[i] = (short)f2bf(fv - bf2f(h));
  }
  *reinterpret_cast<s16x4*>(&Thi[(size_t)(n0 + nrow) * Kd + k0 + kq]) = hi;
  *reinterpret_cast<s16x4*>(&Tlo[(size_t)(n0 + nrow) * Kd + k0 + kq]) = lo;
}

// ---------------- split-bf16 MFMA GEMM, BM=128 BN=64 BK=32 (for proj) ----------------
__global__ __launch_bounds__(256) void k_gemm(const short* __restrict__ Ahi,
                                              const short* __restrict__ Alo,
                                              const short* __restrict__ Bhi,
                                              const short* __restrict__ Blo,
                                              const float* __restrict__ bias,
                                              float* __restrict__ Cout,
                                              int M, int Nn, int Kd) {
  __shared__ __align__(16) short sA[2][128 * 32];
  __shared__ __align__(16) short sB[2][64 * 32];
  const int tid = threadIdx.x;
  const int wv = tid >> 6, l = tid & 63;
  const int lr = l & 15, lg = l >> 4;
  const int row0 = blockIdx.y * 128;
  const int col0 = blockIdx.x * 64;
  const int wr = (wv >> 1) * 64;
  const int wc = (wv & 1) * 32;
  const int ar = tid >> 2, ac = tid & 3;
  f32x4 acc[4][2];
#pragma unroll
  for (int i = 0; i < 4; ++i)
#pragma unroll
    for (int j = 0; j < 2; ++j) acc[i][j] = (f32x4){0.f, 0.f, 0.f, 0.f};

  for (int k0 = 0; k0 < Kd; k0 += 32) {
#pragma unroll
    for (int j = 0; j < 2; ++j) {
      const int row = j * 64 + ar;
      const int cc = ac ^ ((row >> 1) & 3);
      const size_t so = (size_t)(row0 + row) * Kd + k0 + cc * 8;
      GLLDS16(Ahi + so, &sA[0][(j * 256 + (wv << 6)) * 8]);
      GLLDS16(Alo + so, &sA[1][(j * 256 + (wv << 6)) * 8]);
    }
    {
      const int row = ar;
      const int cc = ac ^ ((row >> 1) & 3);
      const size_t so = (size_t)(col0 + row) * Kd + k0 + cc * 8;
      GLLDS16(Bhi + so, &sB[0][(wv << 6) * 8]);
      GLLDS16(Blo + so, &sB[1][(wv << 6) * 8]);
    }
    __syncthreads();
    bf16x8 afh[4], afl[4], bfh[2], bfl[2];
#pragma unroll
    for (int ti = 0; ti < 4; ++ti) {
      const int row = wr + ti * 16 + lr;
      const int pc = lg ^ ((row >> 1) & 3);
      afh[ti] = *reinterpret_cast<const bf16x8*>(&sA[0][row * 32 + pc * 8]);
      afl[ti] = *reinterpret_cast<const bf16x8*>(&sA[1][row * 32 + pc * 8]);
    }
#pragma unroll
    for (int tj = 0; tj < 2; ++tj) {
      const int row = wc + tj * 16 + lr;
      const int pc = lg ^ ((row >> 1) & 3);
      bfh[tj] = *reinterpret_cast<const bf16x8*>(&sB[0][row * 32 + pc * 8]);
      bfl[tj] = *reinterpret_cast<const bf16x8*>(&sB[1][row * 32 + pc * 8]);
    }
#pragma unroll
    for (int ti = 0; ti < 4; ++ti)
#pragma unroll
      for (int tj = 0; tj < 2; ++tj) {
        acc[ti][tj] = MFMA16(afh[ti], bfh[tj], acc[ti][tj]);
        acc[ti][tj] = MFMA16(afl[ti], bfh[tj], acc[ti][tj]);
        acc[ti][tj] = MFMA16(afh[ti], bfl[tj], acc[ti][tj]);
      }
    __syncthreads();
  }
#pragma unroll
  for (int ti = 0; ti < 4; ++ti)
#pragma unroll
    for (int tj = 0; tj < 2; ++tj) {
      const int col = col0 + wc + tj * 16 + lr;
      const float bb = bias[col];
#pragma unroll
      for (int r = 0; r < 4; ++r) {
        const int row = row0 + wr + ti * 16 + lg * 4 + r;
        Cout[(size_t)row * Nn + col] = acc[ti][tj][r] + bb;
      }
    }
}

// ---------------- QKV GEMM (BM=128 BN=128 BK=32) with FUSED post-processing epilogue ----------------
// Each 128-col block covers exactly 2 heads of one part (q/k/v). Epilogue:
// q: split->Qhi/Qlo + row means; k: center by row mean, split->KChi/KClo + means;
// v: bf16 transpose via recycled LDS -> Vt[d][n].
__global__ __launch_bounds__(256) void k_gemm_qkv(const short* __restrict__ Ahi,
                                                  const short* __restrict__ Alo,
                                                  const short* __restrict__ Bhi,
                                                  const short* __restrict__ Blo,
                                                  const float* __restrict__ bias,
                                                  short* __restrict__ Qhi, short* __restrict__ Qlo,
                                                  short* __restrict__ KChi, short* __restrict__ KClo,
                                                  short* __restrict__ Vt,
                                                  float* __restrict__ Qm, float* __restrict__ Km) {
  __shared__ __align__(16) short smem[16384];  // sA(2x4096) | sB(2x4096); recycled for V transpose
  short* sA0 = smem;
  short* sA1 = smem + 4096;
  short* sB0 = smem + 8192;
  short* sB1 = smem + 12288;
  const int Kd = 768;
  const int tid = threadIdx.x;
  const int wv = tid >> 6, l = tid & 63;
  const int lr = l & 15, lg = l >> 4;
  const int row0 = blockIdx.y * 128;
  const int col0 = blockIdx.x * 128;
  const int wr = (wv >> 1) * 64;
  const int wc = (wv & 1) * 64;
  const int ar = tid >> 2, ac = tid & 3;
  f32x4 acc[4][4];
#pragma unroll
  for (int i = 0; i < 4; ++i)
#pragma unroll
    for (int j = 0; j < 4; ++j) acc[i][j] = (f32x4){0.f, 0.f, 0.f, 0.f};

  for (int k0 = 0; k0 < Kd; k0 += 32) {
#pragma unroll
    for (int j = 0; j < 2; ++j) {
      const int row = j * 64 + ar;
      const int cc = ac ^ ((row >> 1) & 3);
      const size_t ao = (size_t)(row0 + row) * Kd + k0 + cc * 8;
      const size_t bo = (size_t)(col0 + row) * Kd + k0 + cc * 8;
      GLLDS16(Ahi + ao, &sA0[(j * 256 + (wv << 6)) * 8]);
      GLLDS16(Alo + ao, &sA1[(j * 256 + (wv << 6)) * 8]);
      GLLDS16(Bhi + bo, &sB0[(j * 256 + (wv << 6)) * 8]);
      GLLDS16(Blo + bo, &sB1[(j * 256 + (wv << 6)) * 8]);
    }
    __syncthreads();
    bf16x8 afh[4], afl[4], bfh[4], bfl[4];
#pragma unroll
    for (int ti = 0; ti < 4; ++ti) {
      const int row = wr + ti * 16 + lr;
      const int pc = lg ^ ((row >> 1) & 3);
      afh[ti] = *reinterpret_cast<const bf16x8*>(&sA0[row * 32 + pc * 8]);
      afl[ti] = *reinterpret_cast<const bf16x8*>(&sA1[row * 32 + pc * 8]);
    }
#pragma unroll
    for (int tj = 0; tj < 4; ++tj) {
      const int row = wc + tj * 16 + lr;
      const int pc = lg ^ ((row >> 1) & 3);
      bfh[tj] = *reinterpret_cast<const bf16x8*>(&sB0[row * 32 + pc * 8]);
      bfl[tj] = *reinterpret_cast<const bf16x8*>(&sB1[row * 32 + pc * 8]);
    }
#pragma unroll
    for (int ti = 0; ti < 4; ++ti)
#pragma unroll
      for (int tj = 0; tj < 4; ++tj) {
        acc[ti][tj] = MFMA16(afh[ti], bfh[tj], acc[ti][tj]);
        acc[ti][tj] = MFMA16(afl[ti], bfh[tj], acc[ti][tj]);
        acc[ti][tj] = MFMA16(afh[ti], bfl[tj], acc[ti][tj]);
      }
    __syncthreads();
  }

  // ---- fused epilogue ----
  const int part = col0 / 768;               // 0=q, 1=k, 2=v
  const int h0 = (col0 - part * 768) >> 6;   // first head of block (even)
  const int b_ = row0 >> 10;
  const int nbase = row0 & 1023;
  const int hh = h0 + (wv & 1);              // this wave's head
  const size_t bh = (size_t)b_ * H_ + hh;
  float bb[4];
#pragma unroll
  for (int tj = 0; tj < 4; ++tj) bb[tj] = bias[col0 + wc + tj * 16 + lr];

  if (part < 2) {
#pragma unroll
    for (int ti = 0; ti < 4; ++ti) {
#pragma unroll
      for (int r = 0; r < 4; ++r) {
        const int n = nbase + wr + ti * 16 + lg * 4 + r;
        float v4[4];
        float s = 0.f;
#pragma unroll
        for (int tj = 0; tj < 4; ++tj) {
          v4[tj] = acc[ti][tj][r] + bb[tj];
          s += v4[tj];
        }
        s += __shfl_xor(s, 1);
        s += __shfl_xor(s, 2);
        s += __shfl_xor(s, 4);
        s += __shfl_xor(s, 8);
        const float mean = s * (1.0f / 64.0f);
        const float sub = part ? mean : 0.0f;
        short* dhi = (part ? KChi : Qhi) + (bh * N_ + n) * D_;
        short* dlo = (part ? KClo : Qlo) + (bh * N_ + n) * D_;
#pragma unroll
        for (int tj = 0; tj < 4; ++tj) {
          const float fv = v4[tj] - sub;
          const unsigned short hb = f2bf(fv);
          const int d = tj * 16 + lr;
          dhi[d] = (short)hb;
          dlo[d] = (short)f2bf(fv - bf2f(hb));
        }
        if (lr == 0) (part ? Km : Qm)[bh * N_ + n] = mean;
      }
    }
  } else {
    // V: stage bf16 transposed into recycled smem (XOR-swizzled [d][row]), then coalesced Vt write
    short* stg = smem + (wv & 1) * 8192;  // per-head 64x128
#pragma unroll
    for (int ti = 0; ti < 4; ++ti)
#pragma unroll
      for (int r = 0; r < 4; ++r) {
        const int row = wr + ti * 16 + lg * 4 + r;
#pragma unroll
        for (int tj = 0; tj < 4; ++tj) {
          const int d = tj * 16 + lr;
          stg[d * 128 + (row ^ ((d & 7) << 3))] = (short)f2bf(acc[ti][tj][r] + bb[tj]);
        }
      }
    __syncthreads();
    for (int slot = tid; slot < 2048; slot += 256) {
      const int hd = slot >> 10;
      const int d = (slot >> 4) & 63;
      const int c8 = (slot & 15) * 8;
      bf16x8 vv = *reinterpret_cast<const bf16x8*>(&smem[hd * 8192 + d * 128 + (c8 ^ ((d & 7) << 3))]);
      const size_t bh2 = (size_t)b_ * H_ + h0 + hd;
      *reinterpret_cast<bf16x8*>(&Vt[(bh2 * D_ + d) * N_ + nbase + c8]) = vv;
    }
  }
}

// ---------------- scores + channel mix -> f16 RESIDUAL logits (+ per-block softmax stats) ----------------
__global__ __launch_bounds__(256, 2) void k_scores(
    const short* __restrict__ Qhi, const short* __restrict__ Qlo,
    const short* __restrict__ KChi, const short* __restrict__ KClo,
    const float* __restrict__ Qm, const float* __restrict__ Km,
    const float* __restrict__ Wfold, float* __restrict__ logits,
    float2* __restrict__ stats) {
  __shared__ __align__(16) short sCh[2][32 * 64];
  __shared__ __align__(16) short sCl[2][32 * 64];
  __shared__ float sQm[12][64];
  __shared__ float sKm[12][32];

  const int t = threadIdx.x;
  const int b = blockIdx.z;
  const int n0 = blockIdx.y * 64, m0 = blockIdx.x * 32;
  const int wv = t >> 6, l = t & 63;
  const int lr = l & 15, lg = l >> 4;
  const size_t bh0 = (size_t)b * H_;

  for (int i = t; i < 768; i += 256)
    sQm[i >> 6][i & 63] = Qm[(bh0 + (i >> 6)) * N_ + n0 + (i & 63)];
  for (int i = t; i < 384; i += 256)
    sKm[i >> 5][i & 31] = Km[(bh0 + (i >> 5)) * N_ + m0 + (i & 31)];

  const int srow = t >> 3;
  const int scs = (t & 7) ^ (srow & 7);
  const size_t csrc = (bh0 * N_ + m0 + srow) * D_ + scs * 8;
  const size_t hstep = (size_t)N_ * D_;
  const int nb = n0 + wv * 16;
  const size_t qsrc = (bh0 * N_ + nb + lr) * D_ + lg * 8;

  GLLDS16(KChi + csrc, &sCh[0][wv * 512]);
  GLLDS16(KClo + csrc, &sCl[0][wv * 512]);
  bf16x8 qh0 = *reinterpret_cast<const bf16x8*>(Qhi + qsrc);
  bf16x8 qh1 = *reinterpret_cast<const bf16x8*>(Qhi + qsrc + 32);
  bf16x8 ql0 = *reinterpret_cast<const bf16x8*>(Qlo + qsrc);
  bf16x8 ql1 = *reinterpret_cast<const bf16x8*>(Qlo + qsrc + 32);

  f32x2 aA01[12], aA23[12], aB01[12], aB23[12];
#pragma unroll
  for (int o = 0; o < 12; ++o) {
    aA01[o] = (f32x2){0.f, 0.f}; aA23[o] = (f32x2){0.f, 0.f};
    aB01[o] = (f32x2){0.f, 0.f}; aB23[o] = (f32x2){0.f, 0.f};
  }

  const int browA = lr, browB = 16 + lr;
  const int aiA0 = browA * 64 + ((lg + 0) ^ (browA & 7)) * 8;
  const int aiA1 = browA * 64 + ((lg + 4) ^ (browA & 7)) * 8;
  const int aiB0 = browB * 64 + ((lg + 0) ^ (browB & 7)) * 8;
  const int aiB1 = browB * 64 + ((lg + 4) ^ (browB & 7)) * 8;
  __syncthreads();

  int buf = 0;
#pragma unroll 2
  for (int h = 0; h < H_; ++h) {
    bf16x8 nqh0, nqh1, nql0, nql1;
    if (h < 11) {
      const size_t cs = csrc + (size_t)(h + 1) * hstep;
      GLLDS16(KChi + cs, &sCh[buf ^ 1][wv * 512]);
      GLLDS16(KClo + cs, &sCl[buf ^ 1][wv * 512]);
      const size_t qs = qsrc + (size_t)(h + 1) * hstep;
      nqh0 = *reinterpret_cast<const bf16x8*>(Qhi + qs);
      nqh1 = *reinterpret_cast<const bf16x8*>(Qhi + qs + 32);
      nql0 = *reinterpret_cast<const bf16x8*>(Qlo + qs);
      nql1 = *reinterpret_cast<const bf16x8*>(Qlo + qs + 32);
    }
    const bf16x8 chA0 = *reinterpret_cast<const bf16x8*>(&sCh[buf][aiA0]);
    const bf16x8 chA1 = *reinterpret_cast<const bf16x8*>(&sCh[buf][aiA1]);
    const bf16x8 clA0 = *reinterpret_cast<const bf16x8*>(&sCl[buf][aiA0]);
    const bf16x8 clA1 = *reinterpret_cast<const bf16x8*>(&sCl[buf][aiA1]);
    const bf16x8 chB0 = *reinterpret_cast<const bf16x8*>(&sCh[buf][aiB0]);
    const bf16x8 chB1 = *reinterpret_cast<const bf16x8*>(&sCh[buf][aiB1]);
    const bf16x8 clB0 = *reinterpret_cast<const bf16x8*>(&sCl[buf][aiB0]);
    const bf16x8 clB1 = *reinterpret_cast<const bf16x8*>(&sCl[buf][aiB1]);

    f32x4 uaA = {0.f, 0.f, 0.f, 0.f}, ubA = {0.f, 0.f, 0.f, 0.f};
    f32x4 uaB = {0.f, 0.f, 0.f, 0.f}, ubB = {0.f, 0.f, 0.f, 0.f};
    uaA = MFMA16(qh0, chA0, uaA);  ubA = MFMA16(qh1, chA1, ubA);
    uaB = MFMA16(qh0, chB0, uaB);  ubB = MFMA16(qh1, chB1, ubB);
    uaA = MFMA16(qh0, clA0, uaA);  ubA = MFMA16(qh1, clA1, ubA);
    uaB = MFMA16(qh0, clB0, uaB);  ubB = MFMA16(qh1, clB1, ubB);
    uaA = MFMA16(ql0, chA0, uaA);  ubA = MFMA16(ql1, chA1, ubA);
    uaB = MFMA16(ql0, chB0, uaB);  ubB = MFMA16(ql1, chB1, ubB);

    const float4 qm4 = *reinterpret_cast<const float4*>(&sQm[h][wv * 16 + lg * 4]);
    const float kmA = 64.0f * sKm[h][lr];
    const float kmB = 64.0f * sKm[h][16 + lr];
    const f32x2 qm01 = {qm4.x, qm4.y};
    const f32x2 qm23 = {qm4.z, qm4.w};
    const f32x2 uA01 = {uaA[0] + ubA[0], uaA[1] + ubA[1]};
    const f32x2 uA23 = {uaA[2] + ubA[2], uaA[3] + ubA[3]};
    const f32x2 uB01 = {uaB[0] + ubB[0], uaB[1] + ubB[1]};
    const f32x2 uB23 = {uaB[2] + ubB[2], uaB[3] + ubB[3]};
    const f32x2 svA01 = kmA * qm01 + uA01;
    const f32x2 svA23 = kmA * qm23 + uA23;
    const f32x2 svB01 = kmB * qm01 + uB01;
    const f32x2 svB23 = kmB * qm23 + uB23;
    const f32x2 u2A01 = uA01 * uA01;
    const f32x2 u2A23 = uA23 * uA23;
    const f32x2 u2B01 = uB01 * uB01;
    const f32x2 u2B23 = uB23 * uB23;
#pragma unroll
    for (int o = 0; o < 12; ++o) {
      const float we = Wfold[o * 24 + h];
      const float wr_ = Wfold[o * 24 + 12 + h];
      aA01[o] = aA01[o] + we * svA01 + wr_ * u2A01;
      aA23[o] = aA23[o] + we * svA23 + wr_ * u2A23;
      aB01[o] = aB01[o] + we * svB01 + wr_ * u2B01;
      aB23[o] = aB23[o] + we * svB23 + wr_ * u2B23;
    }
    __syncthreads();
    buf ^= 1;
    if (h < 11) { qh0 = nqh0; qh1 = nqh1; ql0 = nql0; ql1 = nql1; }
  }

#pragma unroll
  for (int o = 0; o < 12; ++o) {
    float avA[4] = {aA01[o][0], aA01[o][1], aA23[o][0], aA23[o][1]};
    float avB[4] = {aB01[o][0], aB01[o][1], aB23[o][0], aB23[o][1]};
    float M4[4], S4[4];
#pragma unroll
    for (int r = 0; r < 4; ++r) {
      float mxA = avA[r], mxB = avB[r];
      mxA = fmaxf(mxA, __shfl_xor(mxA, 1)); mxB = fmaxf(mxB, __shfl_xor(mxB, 1));
      mxA = fmaxf(mxA, __shfl_xor(mxA, 2)); mxB = fmaxf(mxB, __shfl_xor(mxB, 2));
      mxA = fmaxf(mxA, __shfl_xor(mxA, 4)); mxB = fmaxf(mxB, __shfl_xor(mxB, 4));
      mxA = fmaxf(mxA, __shfl_xor(mxA, 8)); mxB = fmaxf(mxB, __shfl_xor(mxB, 8));
      const float M = fmaxf(mxA, mxB);
      float eA = __expf(avA[r] - M);
      float eB = __expf(avB[r] - M);
      float e = eA + eB;
      e += __shfl_xor(e, 1);
      e += __shfl_xor(e, 2);
      e += __shfl_xor(e, 4);
      e += __shfl_xor(e, 8);
      M4[r] = M; S4[r] = e;
    }
#pragma unroll
    for (int r = 0; r < 4; ++r) {
      short* rowp = (short*)(logits + ((bh0 + o) * N_ + nb + lg * 4 + r) * (size_t)N_);
      rowp[m0 + lr] = f2h(avA[r] - M4[r]);
      rowp[m0 + 16 + lr] = f2h(avB[r] - M4[r]);
    }
    if (lr < 4) {
      const int n = nb + lg * 4 + lr;
      stats[(((size_t)b * 12 + o) * 32 + blockIdx.x) * 1024 + n] = make_float2(M4[lr], S4[lr]);
    }
  }
}

// ---------------- fused stats-merge + softmax-expand (f16 residual -> f32 in-place)
// + PV MFMA (64n x 64m, bf16 V dbuf, DESCENDING m-chunks) ----------------
__global__ __launch_bounds__(256) void k_pvsm(float* __restrict__ attn,
                                              const float2* __restrict__ stats,
                                              const short* __restrict__ Vt,
                                              short* __restrict__ ohi,
                                              short* __restrict__ olo) {
  __shared__ __align__(16) short sPhi[64 * 64];
  __shared__ __align__(16) short sPlo[64 * 64];
  __shared__ __align__(16) short sV[2][64 * 64];
  __shared__ float sIS[64];
  __shared__ short sMseg16[64 * 32];
  const int flat = blockIdx.x + blockIdx.y * 16 + blockIdx.z * 192;
  const int swz = (flat & 7) * 96 + (flat >> 3);
  const int b = swz / 192;
  const int rem = swz - b * 192;
  const int o = rem >> 4;
  const int n0 = (rem & 15) * 64;
  const int bo = b * H_ + o;
  const int t = threadIdx.x;
  const int wv = t >> 6, l = t & 63;
  const int lr = l & 15, lg = l >> 4;
  const int nsub = wv * 16;

  const int vr0 = t >> 3, vr1 = vr0 + 32;
  const int vc0 = (t & 7) ^ (vr0 & 7);
  const int vc1 = (t & 7) ^ (vr1 & 7);
  const size_t vbase = (size_t)bo * D_ * N_;
  const size_t vs0 = vbase + (size_t)vr0 * N_ + vc0 * 8;
  const size_t vs1 = vbase + (size_t)vr1 * N_ + vc1 * 8;

  GLLDS16(Vt + vs0 + 960, &sV[1][(wv * 64) * 8]);
  GLLDS16(Vt + vs1 + 960, &sV[1][(wv * 64 + 256) * 8]);

  if (t < 64) {
    const int n = n0 + t;
    const float2* sp = stats + ((size_t)bo * 32) * 1024 + n;
    float M = -3.0e38f, S = 0.f;
    for (int seg = 0; seg < 32; ++seg) {
      const float2 p = sp[(size_t)seg * 1024];
      if (p.x > M) {
        S = S * __expf(M - p.x) + p.y;
        M = p.x;
      } else {
        S += p.y * __expf(p.x - M);
      }
    }
    sIS[t] = 1.0f / S;
    for (int seg = 0; seg < 32; ++seg)
      sMseg16[t * 32 + seg] = f2h(sp[(size_t)seg * 1024].x - M);
  }

  const int prow = t >> 3, c0 = (t & 7) * 8;
  float* lrowA = attn + ((size_t)bo * N_ + n0 + prow) * N_;
  float* lrowB = attn + ((size_t)bo * N_ + n0 + prow + 32) * N_;
  const int pofsA = prow * 64 + (((t & 7) ^ (prow & 7)) * 8);
  const int pofsB = pofsA + 32 * 64;

  const int arow = nsub + lr;
  const int ai0 = arow * 64 + (((lg + 0) ^ (arow & 7)) * 8);
  const int ai1 = arow * 64 + (((lg + 4) ^ (arow & 7)) * 8);

  f32x4 acc[4];
#pragma unroll
  for (int dt = 0; dt < 4; ++dt) acc[dt] = (f32x4){0.f, 0.f, 0.f, 0.f};
  __syncthreads();

  for (int mc = 15; mc >= 0; --mc) {
    const int m0 = mc * 64;
    if (mc > 0) {
      const int nb2 = (mc - 1) & 1;
      GLLDS16(Vt + vs0 + m0 - 64, &sV[nb2][(wv * 64) * 8]);
      GLLDS16(Vt + vs1 + m0 - 64, &sV[nb2][(wv * 64 + 256) * 8]);
    }
    const int sidx = mc * 2 + ((t & 7) >> 2);
    const float ofsA = h2f(sMseg16[prow * 32 + sidx]);
    const float ofsB = h2f(sMseg16[(prow + 32) * 32 + sidx]);
    const float iSA = sIS[prow], iSB = sIS[prow + 32];
    const bf16x8 rA = *reinterpret_cast<const bf16x8*>(&((const short*)lrowA)[m0 + c0]);
    const bf16x8 rB = *reinterpret_cast<const bf16x8*>(&((const short*)lrowB)[m0 + c0]);
    float pA[8], pB[8];
#pragma unroll
    for (int j = 0; j < 8; ++j) {
      pA[j] = __expf(h2f(rA[j]) + ofsA) * iSA;
      pB[j] = __expf(h2f(rB[j]) + ofsB) * iSB;
    }
    bf16x8 phiA, ploA, phiB, ploB;
#pragma unroll
    for (int j = 0; j < 8; ++j) {
      unsigned short hA = f2bf(pA[j]);
      phiA[j] = (short)hA;
      ploA[j] = (short)f2bf(pA[j] - bf2f(hA));
      unsigned short hB = f2bf(pB[j]);
      phiB[j] = (short)hB;
      ploB[j] = (short)f2bf(pB[j] - bf2f(hB));
    }
    *reinterpret_cast<bf16x8*>(&sPhi[pofsA]) = phiA;
    *reinterpret_cast<bf16x8*>(&sPlo[pofsA]) = ploA;
    *reinterpret_cast<bf16x8*>(&sPhi[pofsB]) = phiB;
    *reinterpret_cast<bf16x8*>(&sPlo[pofsB]) = ploB;
    __syncthreads();

    float4 oaA = {pA[0], pA[1], pA[2], pA[3]};
    float4 obA = {pA[4], pA[5], pA[6], pA[7]};
    float4 oaB = {pB[0], pB[1], pB[2], pB[3]};
    float4 obB = {pB[4], pB[5], pB[6], pB[7]};
    *reinterpret_cast<float4*>(&lrowA[m0 + c0]) = oaA;
    *reinterpret_cast<float4*>(&lrowA[m0 + c0 + 4]) = obA;
    *reinterpret_cast<float4*>(&lrowB[m0 + c0]) = oaB;
    *reinterpret_cast<float4*>(&lrowB[m0 + c0 + 4]) = obB;

    const int cur = mc & 1;
    const bf16x8 pah0 = *reinterpret_cast<const bf16x8*>(&sPhi[ai0]);
    const bf16x8 pah1 = *reinterpret_cast<const bf16x8*>(&sPhi[ai1]);
    const bf16x8 pal0 = *reinterpret_cast<const bf16x8*>(&sPlo[ai0]);
    const bf16x8 pal1 = *reinterpret_cast<const bf16x8*>(&sPlo[ai1]);
#pragma unroll
    for (int dt = 0; dt < 4; ++dt) {
      const int drow = dt * 16 + lr;
      const bf16x8 vh0 = *reinterpret_cast<const bf16x8*>(&sV[cur][drow * 64 + (((lg + 0) ^ (drow & 7)) * 8)]);
      const bf16x8 vh1 = *reinterpret_cast<const bf16x8*>(&sV[cur][drow * 64 + (((lg + 4) ^ (drow & 7)) * 8)]);
      acc[dt] = MFMA16(pah0, vh0, acc[dt]);
      acc[dt] = MFMA16(pal0, vh0, acc[dt]);
      acc[dt] = MFMA16(pah1, vh1, acc[dt]);
      acc[dt] = MFMA16(pal1, vh1, acc[dt]);
    }
    __syncthreads();
  }
#pragma unroll
  for (int dt = 0; dt < 4; ++dt) {
    const int d = dt * 16 + lr;
#pragma unroll
    for (int r = 0; r < 4; ++r) {
      const int n = n0 + nsub + lg * 4 + r;
      const float val = acc[dt][r];
      const unsigned short hh = f2bf(val);
      const size_t oo = (size_t)(b * 1024 + n) * 768 + o * 64 + d;
      ohi[oo] = (short)hh;
      olo[oo] = (short)f2bf(val - bf2f(hh));
    }
  }
}

extern "C" void kernel_launch(void* const* d_in, const int* in_sizes, int n_in,
                              void* d_out, int out_size, void* d_ws, size_t ws_size,
                              hipStream_t stream) {
  (void)in_sizes; (void)n_in; (void)out_size; (void)ws_size;
  const float* x      = (const float*)d_in[0];
  const float* W_qkv  = (const float*)d_in[1];
  const float* b_qkv  = (const float*)d_in[2];
  const float* scale  = (const float*)d_in[3];
  const float* riem   = (const float*)d_in[4];
  const float* W_conv = (const float*)d_in[5];
  // d_in[6] = b_conv: constant along softmax axis -> softmax-invariant, skipped
  const float* W_proj = (const float*)d_in[7];
  const float* b_proj = (const float*)d_in[8];

  float* out_final = (float*)d_out;                     // [B,N,C]
  float* attn_out  = out_final + (size_t)B_ * N_ * C_;  // [B,H,N,N] f16 residuals -> f32 attn in-place

  char* w = (char*)d_ws;
  short* xhi   = (short*)w;                        // 6291456 B
  short* xlo   = (short*)(w + 6291456);            // 6291456 B
  short* Wthi  = (short*)(w + 12582912);           // 3538944 B
  short* Wtlo  = (short*)(w + 16121856);           // 3538944 B
  short* Wpthi = (short*)(w + 19660800);           // 1179648 B
  short* Wptlo = (short*)(w + 20840448);           // 1179648 B
  short* Qhi   = (short*)(w + 22020096);           // 6291456 B
  short* Qlo   = (short*)(w + 28311552);           // 6291456 B
  short* KChi  = (short*)(w + 34603008);           // 6291456 B
  short* KClo  = (short*)(w + 40894464);           // 6291456 B
  short* Vt    = (short*)(w + 47185920);           // 6291456 B
  float* Qm    = (float*)(w + 53477376);           // 196608 B
  float* Km    = (float*)(w + 53673984);           // 196608 B
  float* Wfold = (float*)(w + 53870592);           // 1152 B (pad to 4096)
  float2* stats = (float2*)(w + 53874688);         // 12582912 B -> ends 66457600
  short* ohi = Qhi;                                // after k_scores, Q splits dead
  short* olo = Qlo;

  k_prep<<<dim3(3841), 256, 0, stream>>>(x, xhi, xlo, W_qkv, Wthi, Wtlo, W_proj, Wpthi, Wptlo,
                                         W_conv, scale, riem, Wfold);
  k_gemm_qkv<<<dim3(18, 32), 256, 0, stream>>>(xhi, xlo, Wthi, Wtlo, b_qkv,
                                               Qhi, Qlo, KChi, KClo, Vt, Qm, Km);
  k_scores<<<dim3(32, 16, 4), 256, 0, stream>>>(Qhi, Qlo, KChi, KClo, Qm, Km, Wfold, attn_out, stats);
  k_pvsm<<<dim3(16, 12, 4), 256, 0, stream>>>(attn_out, stats, Vt, ohi, olo);
  k_gemm<<<dim3(12, 32), 256, 0, stream>>>(ohi, olo, Wpthi, Wptlo, b_proj, out_final, 4096, 768, 768);
}